// Round 13
// baseline (289.487 us; speedup 1.0000x reference)
//
#include <hip/hip_runtime.h>

typedef unsigned short ushort_t;
typedef __attribute__((ext_vector_type(8))) short short8;
typedef __attribute__((ext_vector_type(4))) float f32x4;

#define BT 4096
#define TSEQ 2048
#define CC 1024
#define NH 16
#define DH 64
#define HID 4096
#define ATT_SCALE 0.03125f   /* C^-0.5 = 1/32 (reference scales by C, not DH) */

__device__ __forceinline__ ushort_t f2bf(float f) {
    unsigned u = __float_as_uint(f);
    u = u + 0x7fffu + ((u >> 16) & 1u);
    return (ushort_t)(u >> 16);
}
__device__ __forceinline__ float bf2f(ushort_t u) {
    return __uint_as_float(((unsigned)u) << 16);
}

typedef const __attribute__((address_space(1))) unsigned int* gptr_t;
typedef __attribute__((address_space(3))) unsigned int* lptr_t;
__device__ __forceinline__ void gload_lds16(const void* g, void* l) {
    __builtin_amdgcn_global_load_lds((gptr_t)g, (lptr_t)l, 16, 0, 0);
}

template <int N> __device__ __forceinline__ void vmcnt_wait() {
    if constexpr (N == 0)      asm volatile("s_waitcnt vmcnt(0)" ::: "memory");
    else if constexpr (N == 2) asm volatile("s_waitcnt vmcnt(2)" ::: "memory");
    else if constexpr (N == 3) asm volatile("s_waitcnt vmcnt(3)" ::: "memory");
    else if constexpr (N == 4) asm volatile("s_waitcnt vmcnt(4)" ::: "memory");
    else if constexpr (N == 6) asm volatile("s_waitcnt vmcnt(6)" ::: "memory");
    else static_assert(N == 0, "unsupported vmcnt");
}

#define LGKM0 do { asm volatile("s_waitcnt lgkmcnt(0)" ::: "memory"); \
                   __builtin_amdgcn_sched_barrier(0); } while (0)
#define SBAR  do { __builtin_amdgcn_sched_barrier(0); \
                   __builtin_amdgcn_s_barrier(); } while (0)

// ---------------------------------------------------------------------------
// Tiled transpose + f32->bf16 convert:  in [R][Cn] f32  ->  out [Cn][R] bf16
// ---------------------------------------------------------------------------
__global__ __launch_bounds__(256) void transpose_cvt(
    const float* __restrict__ in, ushort_t* __restrict__ out, int R, int Cn)
{
    __shared__ float tile[32][33];
    size_t off = (size_t)blockIdx.z * R * Cn;
    int c0 = blockIdx.x * 32, r0 = blockIdx.y * 32;
    int tx = threadIdx.x & 31, ty = threadIdx.x >> 5;
#pragma unroll
    for (int q = 0; q < 4; ++q)
        tile[ty + 8 * q][tx] = in[off + (size_t)(r0 + ty + 8 * q) * Cn + c0 + tx];
    __syncthreads();
#pragma unroll
    for (int q = 0; q < 4; ++q)
        out[off + (size_t)(c0 + ty + 8 * q) * R + r0 + tx] = f2bf(tile[tx][ty + 8 * q]);
}

// QKV weight transpose, merged: z = mat*16 + head; [C][64] -> [64][C] per head
__global__ __launch_bounds__(256) void transpose_qkv(
    const float* __restrict__ Wq, const float* __restrict__ Wk,
    const float* __restrict__ Wv, ushort_t* __restrict__ WqkvT)
{
    __shared__ float tile[32][33];
    int z = blockIdx.z, mat = z >> 4, head = z & 15;
    const float* in = (mat == 0 ? Wq : (mat == 1 ? Wk : Wv)) + (size_t)head * CC * DH;
    ushort_t* out = WqkvT + (size_t)z * DH * CC;
    int c0 = blockIdx.x * 32, r0 = blockIdx.y * 32;
    int tx = threadIdx.x & 31, ty = threadIdx.x >> 5;
#pragma unroll
    for (int q = 0; q < 4; ++q)
        tile[ty + 8 * q][tx] = in[(size_t)(r0 + ty + 8 * q) * DH + c0 + tx];
    __syncthreads();
#pragma unroll
    for (int q = 0; q < 4; ++q)
        out[(size_t)(c0 + ty + 8 * q) * CC + r0 + tx] = f2bf(tile[tx][ty + 8 * q]);
}

// ---------------------------------------------------------------------------
// LayerNorm row kernel: x f32 [rows][1024] -> out bf16.
// ---------------------------------------------------------------------------
__global__ __launch_bounds__(256) void ln_kernel(
    const float* __restrict__ x, const float* __restrict__ g,
    const float* __restrict__ b, ushort_t* __restrict__ out)
{
    int row = blockIdx.x;
    const float4 xv = ((const float4*)(x + (size_t)row * CC))[threadIdx.x];
    float s = xv.x + xv.y + xv.z + xv.w;
    float s2 = xv.x * xv.x + xv.y * xv.y + xv.z * xv.z + xv.w * xv.w;
#pragma unroll
    for (int d = 1; d < 64; d <<= 1) {
        s += __shfl_xor(s, d);
        s2 += __shfl_xor(s2, d);
    }
    __shared__ float ps[4], ps2[4];
    int w = threadIdx.x >> 6, lane = threadIdx.x & 63;
    if (lane == 0) { ps[w] = s; ps2[w] = s2; }
    __syncthreads();
    s = ps[0] + ps[1] + ps[2] + ps[3];
    s2 = ps2[0] + ps2[1] + ps2[2] + ps2[3];
    float mu = s * (1.0f / CC);
    float var = s2 * (1.0f / CC) - mu * mu;
    float rs = rsqrtf(var + 1e-5f);
    int c = threadIdx.x * 4;
    const float4 gv = ((const float4*)g)[threadIdx.x];
    const float4 bv = ((const float4*)b)[threadIdx.x];
    ushort_t u0 = f2bf((xv.x - mu) * rs * gv.x + bv.x);
    ushort_t u1 = f2bf((xv.y - mu) * rs * gv.y + bv.y);
    ushort_t u2 = f2bf((xv.z - mu) * rs * gv.z + bv.z);
    ushort_t u3 = f2bf((xv.w - mu) * rs * gv.w + bv.w);
    unsigned lo = (unsigned)u0 | ((unsigned)u1 << 16);
    unsigned hi = (unsigned)u2 | ((unsigned)u3 << 16);
    ((uint2*)(out + (size_t)row * CC + c))[0] = make_uint2(lo, hi);
}

// ---------------------------------------------------------------------------
// 256x256 / BK=64 GEMM, 512 threads (8 waves 2Mx4N, 128x64 per wave),
// 4-phase/K-tile schedule (m201 template): per phase {stage 1 half-tile of
// tile t+1 || ds_read quadrant frags || 16 MFMA}, ONE counted vmcnt(2) per
// K-tile at phase 0 (never 0 in main loop), st-swizzled LDS (zero conflicts).
// MODE 1: bf16 out = relu(acc + bias[n])
// MODE 2: QKV scatter (Q prescaled by ATT_SCALE)
// MODE 3: split-K bf16 partial at plane blockIdx.z (A/B column offset z*K)
// ---------------------------------------------------------------------------
template <int MODE>
__global__ __launch_bounds__(512) void gemm256(
    const ushort_t* __restrict__ A, const ushort_t* __restrict__ Bt,
    int N, int K, int lda, int ldb, const float* __restrict__ bias,
    void* __restrict__ out0, void* __restrict__ out1, void* __restrict__ out2)
{
    __shared__ char AsB[2][32768];   // [buf][half*16384 + row*128 + byte]
    __shared__ char BsB[2][32768];

    const int t = threadIdx.x;
    const int wid = t >> 6, lane = t & 63, g = lane >> 4, c = lane & 15;
    const int wr = wid >> 2, wc = wid & 3;
    const int m0 = blockIdx.x * 256;
    const int n0 = blockIdx.y * 256;
    if (MODE == 3) {
        A += (size_t)blockIdx.z * K;
        Bt += (size_t)blockIdx.z * K;
    }

    f32x4 acc[8][4];
#pragma unroll
    for (int am = 0; am < 8; ++am)
#pragma unroll
        for (int an = 0; an < 4; ++an) acc[am][an] = f32x4{0.f, 0.f, 0.f, 0.f};

    const int srow = t >> 3, sbyte = (t & 7) * 16;   // staging coords
    const int rbB = (wc & 1) * 64;                    // B local-row base
    short8 af[4][2], bf[2][2];

// stage one 128-row half-tile (2 gloads/thread), inverse-swizzled source
#define STG(PTR, LD, BROW, DST, HOFF, TI)                                        \
    { _Pragma("unroll") for (int j = 0; j < 2; ++j) {                            \
        int r = j * 64 + srow;                                                   \
        int bs = sbyte ^ ((r & 7) << 4);                                         \
        gload_lds16((const char*)(PTR) +                                         \
                        ((size_t)((BROW) + r) * (LD) + (size_t)(TI) * 64) * 2 + bs, \
                    (DST) + (HOFF) + r * 128 + sbyte); } }

#define DSAF(BUF, MH)                                                            \
    { const char* ab = AsB[BUF] + wr * 16384;                                    \
      _Pragma("unroll") for (int mi = 0; mi < 4; ++mi) {                         \
        int ra = (MH) * 64 + mi * 16 + c;                                        \
        _Pragma("unroll") for (int ks = 0; ks < 2; ++ks)                         \
            af[mi][ks] = *(const short8*)(ab + ra * 128 +                        \
                (((unsigned)(ks * 64 + g * 16)) ^ ((unsigned)((ra & 7) << 4)))); } }

#define DSBF(BUF, NH)                                                            \
    { const char* bb = BsB[BUF] + (wc >> 1) * 16384;                             \
      _Pragma("unroll") for (int ni = 0; ni < 2; ++ni) {                         \
        int rb = rbB + (NH) * 32 + ni * 16 + c;                                  \
        _Pragma("unroll") for (int ks = 0; ks < 2; ++ks)                         \
            bf[ni][ks] = *(const short8*)(bb + rb * 128 +                        \
                (((unsigned)(ks * 64 + g * 16)) ^ ((unsigned)((rb & 7) << 4)))); } }

#define MFMAQ(MH, NH)                                                            \
    __builtin_amdgcn_s_setprio(1);                                               \
    _Pragma("unroll") for (int mi = 0; mi < 4; ++mi)                             \
    _Pragma("unroll") for (int ni = 0; ni < 2; ++ni)                             \
    _Pragma("unroll") for (int ks = 0; ks < 2; ++ks)                             \
        acc[(MH) * 4 + mi][(NH) * 2 + ni] = __builtin_amdgcn_mfma_f32_16x16x32_bf16( \
            af[mi][ks], bf[ni][ks], acc[(MH) * 4 + mi][(NH) * 2 + ni], 0, 0, 0); \
    __builtin_amdgcn_s_setprio(0);

    const int nt = K >> 6;
    // prologue: stage all 4 halves of tile 0 into buf 0 (8 loads)
    STG(A,  lda, m0,        AsB[0], 0,     0);
    STG(A,  lda, m0 + 128,  AsB[0], 16384, 0);
    STG(Bt, ldb, n0,        BsB[0], 0,     0);
    STG(Bt, ldb, n0 + 128,  BsB[0], 16384, 0);

    for (int ti = 0; ti < nt; ++ti) {
        const int b = ti & 1, nb = b ^ 1;
        const bool more = (ti + 1 < nt);
        // ---- phase 0: stage A-half0(t+1); counted wait certifies tile t ----
        if (more) { STG(A, lda, m0, AsB[nb], 0, ti + 1); vmcnt_wait<2>(); }
        else        vmcnt_wait<0>();
        SBAR;                              // buf b certified for ALL waves
        DSAF(b, 0); DSBF(b, 0);
        LGKM0;
        MFMAQ(0, 0);
        SBAR;
        // ---- phase 1: stage A-half1(t+1) ----
        if (more) STG(A, lda, m0 + 128, AsB[nb], 16384, ti + 1);
        DSBF(b, 1);
        SBAR;
        LGKM0;
        MFMAQ(0, 1);
        SBAR;
        // ---- phase 2: stage B-half0(t+1) ----
        if (more) STG(Bt, ldb, n0, BsB[nb], 0, ti + 1);
        DSAF(b, 1); DSBF(b, 0);
        SBAR;
        LGKM0;
        MFMAQ(1, 0);
        SBAR;
        // ---- phase 3: stage B-half1(t+1) ----
        if (more) STG(Bt, ldb, n0 + 128, BsB[nb], 16384, ti + 1);
        DSBF(b, 1);
        SBAR;
        LGKM0;
        MFMAQ(1, 1);
        SBAR;
    }
#undef STG
#undef DSAF
#undef DSBF
#undef MFMAQ

#pragma unroll
    for (int am = 0; am < 8; ++am)
#pragma unroll
        for (int an = 0; an < 4; ++an)
#pragma unroll
            for (int i = 0; i < 4; ++i) {
                int row = m0 + wr * 128 + am * 16 + g * 4 + i;
                int col = n0 + wc * 64 + an * 16 + c;
                float v = acc[am][an][i];
                if (MODE == 1) {
                    v += bias[col];
                    v = v > 0.f ? v : 0.f;
                    ((ushort_t*)out0)[(size_t)row * N + col] = f2bf(v);
                } else if (MODE == 3) {
                    ((ushort_t*)out0)[(size_t)blockIdx.z * BT * N + (size_t)row * N + col] =
                        f2bf(v);
                } else {
                    int bb = row >> 11, tt = row & (TSEQ - 1);
                    if (col < 1024) {
                        int head = col >> 6, d = col & 63;
                        ((ushort_t*)out0)[((size_t)(bb * NH + head) * TSEQ + tt) * DH + d] =
                            f2bf(v * ATT_SCALE);
                    } else if (col < 2048) {
                        int head = (col - 1024) >> 6, d = col & 63;
                        ((ushort_t*)out1)[((size_t)(bb * NH + head) * TSEQ + tt) * DH + d] = f2bf(v);
                    } else {
                        int head = (col - 2048) >> 6, d = col & 63;
                        ((ushort_t*)out2)[((size_t)(bb * NH + head) * DH + d) * TSEQ + tt] = f2bf(v);
                    }
                }
            }
}

// ---------------------------------------------------------------------------
// LDS-staged NT GEMM (128-wide, counted-vmcnt ring) -- kept for out-proj.
// MODE 0: f32 out = acc + bias[n] + resid[m][n]
// ---------------------------------------------------------------------------
template <int BM, int BN, int WM, int WN, int MR, int NR, int MODE, int D>
__global__ __launch_bounds__(256) void gemm_tile(
    const ushort_t* __restrict__ A, const ushort_t* __restrict__ Bt,
    int N, int K, int lda, int ldb,
    const float* __restrict__ bias, const float* __restrict__ resid,
    void* __restrict__ out0)
{
    static_assert(WM * WN == 4 && WM * MR * 16 == BM && WN * NR * 16 == BN, "geom");
    constexpr int L = BM / 64 + BN / 64;
    __shared__ ushort_t As[D][BM * 32];
    __shared__ ushort_t Bs[D][BN * 32];

    const int t = threadIdx.x;
    const int w = t >> 6, lane = t & 63, g = lane >> 4, c = lane & 15;
    const int wr = w / WN, wc = w % WN;
    const int m0 = blockIdx.x * BM;
    const int n0 = blockIdx.y * BN;

    f32x4 acc[MR][NR];
#pragma unroll
    for (int mi = 0; mi < MR; ++mi)
#pragma unroll
        for (int ni = 0; ni < NR; ++ni) acc[mi][ni] = f32x4{0.f, 0.f, 0.f, 0.f};

    const int arow = t >> 2, acol = (t & 3) * 8;
    const int aoff = (wr * MR * 16 + c) * 32 + g * 8;
    const int boff = (wc * NR * 16 + c) * 32 + g * 8;

#define STAGE(BUF, K0)                                                          \
    {                                                                           \
        _Pragma("unroll") for (int j = 0; j < BM / 64; ++j)                     \
            gload_lds16(A + (size_t)(m0 + j * 64 + arow) * lda + (K0) + acol,   \
                        As[BUF] + (size_t)j * 2048 + t * 8);                    \
        _Pragma("unroll") for (int j = 0; j < BN / 64; ++j)                     \
            gload_lds16(Bt + (size_t)(n0 + j * 64 + arow) * ldb + (K0) + acol,  \
                        Bs[BUF] + (size_t)j * 2048 + t * 8);                    \
    }

    const int nt = K >> 5;
#pragma unroll
    for (int d = 0; d < D - 1; ++d) STAGE(d, d * 32);

    int cur = 0;
    for (int ti = 0; ti < nt; ++ti) {
        const int ahead = nt - 1 - ti;
        if (ahead >= D - 1) {
            const int stg = (cur == 0) ? D - 1 : cur - 1;
            STAGE(stg, (ti + D - 1) * 32);
            vmcnt_wait<(D - 1) * L>();
        } else if (D == 3 && ahead == 1) {
            vmcnt_wait<L>();
        } else {
            vmcnt_wait<0>();
        }
        SBAR;

        const ushort_t* Ard = As[cur] + aoff;
        const ushort_t* Brd = Bs[cur] + boff;
        short8 af[MR], bf[NR];
#pragma unroll
        for (int mi = 0; mi < MR; ++mi) af[mi] = *(const short8*)(Ard + mi * 512);
#pragma unroll
        for (int ni = 0; ni < NR; ++ni) bf[ni] = *(const short8*)(Brd + ni * 512);
        __builtin_amdgcn_s_setprio(1);
#pragma unroll
        for (int mi = 0; mi < MR; ++mi)
#pragma unroll
            for (int ni = 0; ni < NR; ++ni)
                acc[mi][ni] = __builtin_amdgcn_mfma_f32_16x16x32_bf16(
                    af[mi], bf[ni], acc[mi][ni], 0, 0, 0);
        __builtin_amdgcn_s_setprio(0);

        SBAR;
        cur = (cur + 1 == D) ? 0 : cur + 1;
    }
#undef STAGE

#pragma unroll
    for (int mi = 0; mi < MR; ++mi)
#pragma unroll
        for (int ni = 0; ni < NR; ++ni)
#pragma unroll
            for (int i = 0; i < 4; ++i) {
                int row = m0 + wr * MR * 16 + mi * 16 + g * 4 + i;
                int col = n0 + wc * NR * 16 + ni * 16 + c;
                float v = acc[mi][ni][i] + bias[col] + resid[(size_t)row * N + col];
                ((float*)out0)[(size_t)row * N + col] = v;
            }
}

// ---------------------------------------------------------------------------
// FFN2 combine: out[m][n] = sum_{z<4} bf16 parts[z][m][n] + bias[n] + resid
// ---------------------------------------------------------------------------
__global__ __launch_bounds__(256) void ffn2_combine(
    const ushort_t* __restrict__ parts, const float* __restrict__ bias,
    const float* __restrict__ resid, float* __restrict__ out)
{
    const size_t off = ((size_t)blockIdx.x * 256 + threadIdx.x) * 8;
    const int col = (int)(off & 1023);
    short8 p0 = *(const short8*)(parts + off);
    short8 p1 = *(const short8*)(parts + (size_t)BT * CC + off);
    short8 p2 = *(const short8*)(parts + (size_t)2 * BT * CC + off);
    short8 p3 = *(const short8*)(parts + (size_t)3 * BT * CC + off);
    float4 r0 = ((const float4*)(resid + off))[0];
    float4 r1 = ((const float4*)(resid + off + 4))[0];
    float4 b0 = ((const float4*)(bias + col))[0];
    float4 b1 = ((const float4*)(bias + col + 4))[0];
    float o[8];
#pragma unroll
    for (int j = 0; j < 8; ++j)
        o[j] = bf2f((ushort_t)p0[j]) + bf2f((ushort_t)p1[j]) +
               bf2f((ushort_t)p2[j]) + bf2f((ushort_t)p3[j]);
    float4 w0 = make_float4(o[0] + b0.x + r0.x, o[1] + b0.y + r0.y,
                            o[2] + b0.z + r0.z, o[3] + b0.w + r0.w);
    float4 w1 = make_float4(o[4] + b1.x + r1.x, o[5] + b1.y + r1.y,
                            o[6] + b1.z + r1.z, o[7] + b1.w + r1.w);
    ((float4*)(out + off))[0] = w0;
    ((float4*)(out + off + 4))[0] = w1;
}

// ---------------------------------------------------------------------------
// Split flash: K/V tiles staged per block into LDS (global_load_lds,
// inverse-swizzled source), shared by 4 waves.  grid (B*H, T/64, 4 chunks).
// ---------------------------------------------------------------------------
__global__ __launch_bounds__(256) void flash_split(
    const ushort_t* __restrict__ Q, const ushort_t* __restrict__ Kb,
    const ushort_t* __restrict__ Vt, float* __restrict__ opart,
    float* __restrict__ mlpart, ushort_t* __restrict__ attout)
{
    __shared__ ushort_t Ks[64 * 64];
    __shared__ ushort_t Vs[64 * 64];
    __shared__ ushort_t Plds[4][16 * 72];
    const int t = threadIdx.x;
    const int w = t >> 6, lane = t & 63;
    const int g = lane >> 4, c = lane & 15;
    const int bh = blockIdx.x, qb = blockIdx.y, sc = blockIdx.z;
    if (sc * 8 > qb) return;
    const int bb = bh >> 4, hh = bh & 15;
    const int q0 = qb * 64 + w * 16;
    const ushort_t* qp = Q + (size_t)bh * TSEQ * DH;
    const char* kpB = (const char*)(Kb + (size_t)bh * TSEQ * DH);
    const char* vpB = (const char*)(Vt + (size_t)bh * DH * TSEQ);

    const short8 bq0 = *(const short8*)(qp + (size_t)(q0 + c) * DH + g * 8);
    const short8 bq1 = *(const short8*)(qp + (size_t)(q0 + c) * DH + 32 + g * 8);

    float m_ = -INFINITY, l_ = 0.f;
    f32x4 o[4];
#pragma unroll
    for (int nf = 0; nf < 4; ++nf) o[nf] = f32x4{0.f, 0.f, 0.f, 0.f};

    const int st0 = sc * 8;
    const int send = (st0 + 7 < qb) ? st0 + 7 : qb;
    ushort_t* pw = &Plds[w][c * 72];
    const unsigned bxor = (unsigned)((c & 7) << 4);

    const int srow = t >> 3, sb = (t & 7) * 16;
#define STAGE_KV(ST)                                                                \
    {                                                                               \
        const int S0_ = (ST) * 64;                                                  \
        _Pragma("unroll") for (int j = 0; j < 2; ++j) {                             \
            int r = j * 32 + srow;                                                  \
            int bs = sb ^ ((r & 7) << 4);                                           \
            gload_lds16(kpB + (size_t)(S0_ + r) * 128 + bs,                         \
                        (char*)Ks + r * 128 + sb);                                  \
            gload_lds16(vpB + (size_t)r * (TSEQ * 2) + S0_ * 2 + bs,                \
                        (char*)Vs + r * 128 + sb);                                  \
        }                                                                           \
    }

    STAGE_KV(st0);
    for (int st = st0; st <= send; ++st) {
        const int S0 = st * 64;
        __syncthreads();

        __builtin_amdgcn_s_setprio(1);
        f32x4 sa[4];
#pragma unroll
        for (int sub = 0; sub < 4; ++sub) {
            const char* kr = (const char*)Ks + (16 * sub + c) * 128;
            short8 k0 = *(const short8*)(kr + ((g * 16) ^ bxor));
            short8 k1 = *(const short8*)(kr + ((64 + g * 16) ^ bxor));
            f32x4 t0 = f32x4{0.f, 0.f, 0.f, 0.f};
            t0 = __builtin_amdgcn_mfma_f32_16x16x32_bf16(k0, bq0, t0, 0, 0, 0);
            t0 = __builtin_amdgcn_mfma_f32_16x16x32_bf16(k1, bq1, t0, 0, 0, 0);
            sa[sub] = t0;
        }
        __builtin_amdgcn_s_setprio(0);

        float pvv[16];
#pragma unroll
        for (int sub = 0; sub < 4; ++sub)
#pragma unroll
            for (int i = 0; i < 4; ++i) pvv[4 * sub + i] = sa[sub][i];
        if (st == qb) {
#pragma unroll
            for (int sub = 0; sub < 4; ++sub)
#pragma unroll
                for (int i = 0; i < 4; ++i)
                    if (S0 + 16 * sub + 4 * g + i > q0 + c) pvv[4 * sub + i] = -INFINITY;
        }
        float tmax = pvv[0];
#pragma unroll
        for (int j = 1; j < 16; ++j) tmax = fmaxf(tmax, pvv[j]);
        tmax = fmaxf(tmax, __shfl_xor(tmax, 16));
        tmax = fmaxf(tmax, __shfl_xor(tmax, 32));
        if (!__all(tmax - m_ <= 8.0f)) {
            float mn = fmaxf(m_, tmax);
            float fac = __expf(m_ - mn);
            m_ = mn;
            l_ *= fac;
#pragma unroll
            for (int i = 0; i < 4; ++i) {
                float fr = __shfl(fac, 4 * g + i);
#pragma unroll
                for (int nf = 0; nf < 4; ++nf) o[nf][i] *= fr;
            }
        }
        float pp[16], rs = 0.f;
#pragma unroll
        for (int j = 0; j < 16; ++j) { pp[j] = __expf(pvv[j] - m_); rs += pp[j]; }
        rs += __shfl_xor(rs, 16);
        rs += __shfl_xor(rs, 32);
        l_ += rs;

#pragma unroll
        for (int sub = 0; sub < 4; ++sub) {
            unsigned lo = (__float_as_uint(pp[4 * sub + 0]) >> 16) |
                          (__float_as_uint(pp[4 * sub + 1]) & 0xffff0000u);
            unsigned hi = (__float_as_uint(pp[4 * sub + 2]) >> 16) |
                          (__float_as_uint(pp[4 * sub + 3]) & 0xffff0000u);
            *(uint2*)(pw + 16 * sub + 4 * g) = make_uint2(lo, hi);
        }
        asm volatile("s_waitcnt lgkmcnt(0)" ::: "memory");
        short8 pa0 = *(const short8*)(&Plds[w][c * 72 + g * 8]);
        short8 pa1 = *(const short8*)(&Plds[w][c * 72 + 32 + g * 8]);

        __builtin_amdgcn_s_setprio(1);
#pragma unroll
        for (int nf = 0; nf < 4; ++nf) {
            const char* vr = (const char*)Vs + (nf * 16 + c) * 128;
            short8 v0 = *(const short8*)(vr + ((g * 16) ^ bxor));
            short8 v1 = *(const short8*)(vr + ((64 + g * 16) ^ bxor));
            o[nf] = __builtin_amdgcn_mfma_f32_16x16x32_bf16(pa0, v0, o[nf], 0, 0, 0);
            o[nf] = __builtin_amdgcn_mfma_f32_16x16x32_bf16(pa1, v1, o[nf], 0, 0, 0);
        }
        __builtin_amdgcn_s_setprio(0);

        __syncthreads();
        if (st < send) STAGE_KV(st + 1);
    }
#undef STAGE_KV

    if (qb < 8) {
#pragma unroll
        for (int i = 0; i < 4; ++i) {
            float rl = 1.0f / __shfl(l_, 4 * g + i);
            int tt = q0 + 4 * g + i;
#pragma unroll
            for (int nf = 0; nf < 4; ++nf)
                attout[((size_t)(bb * TSEQ + tt)) * CC + hh * DH + nf * 16 + c] =
                    f2bf(o[nf][i] * rl);
        }
    } else {
        const size_t slot = (size_t)(bh * 32 + qb) * 4 + sc;
        float* op = opart + slot * 4096;
#pragma unroll
        for (int nf = 0; nf < 4; ++nf)
#pragma unroll
            for (int i = 0; i < 4; ++i)
                op[(size_t)(w * 16 + 4 * g + i) * 64 + nf * 16 + c] = o[nf][i];
        if (g == 0) {
            mlpart[slot * 128 + w * 16 + c] = m_;
            mlpart[slot * 128 + 64 + w * 16 + c] = l_;
        }
    }
}

// ---------------------------------------------------------------------------
// Combine partials for qb >= 8.  grid (B*H, 24) -> qb = blockIdx.y + 8.
// ---------------------------------------------------------------------------
__global__ __launch_bounds__(256) void flash_combine(
    const float* __restrict__ opart, const float* __restrict__ mlpart,
    ushort_t* __restrict__ attout)
{
    const int bh = blockIdx.x, qb = blockIdx.y + 8;
    const int bb = bh >> 4, hh = bh & 15;
    const int nsc = (qb >> 3) + 1;
    const int t = threadIdx.x, r = t >> 2, qc = t & 3;
    const size_t slot0 = (size_t)(bh * 32 + qb) * 4;

    float mi[4], li[4];
    float M = -INFINITY;
#pragma unroll
    for (int i = 0; i < 4; ++i) {
        if (i < nsc) {
            mi[i] = mlpart[(slot0 + i) * 128 + r];
            li[i] = mlpart[(slot0 + i) * 128 + 64 + r];
            M = fmaxf(M, mi[i]);
        }
    }
    float L = 0.f;
    f32x4 acc[4];
#pragma unroll
    for (int j = 0; j < 4; ++j) acc[j] = f32x4{0.f, 0.f, 0.f, 0.f};
#pragma unroll
    for (int i = 0; i < 4; ++i) {
        if (i < nsc) {
            float F = __expf(mi[i] - M);
            L += li[i] * F;
            const f32x4* orow = (const f32x4*)(opart + (slot0 + i) * 4096 +
                                               (size_t)r * 64 + qc * 16);
#pragma unroll
            for (int j = 0; j < 4; ++j) acc[j] += orow[j] * F;
        }
    }
    float rl = 1.0f / L;
    unsigned wb[8];
#pragma unroll
    for (int j = 0; j < 4; ++j) {
        wb[2 * j] = (unsigned)f2bf(acc[j][0] * rl) | ((unsigned)f2bf(acc[j][1] * rl) << 16);
        wb[2 * j + 1] = (unsigned)f2bf(acc[j][2] * rl) | ((unsigned)f2bf(acc[j][3] * rl) << 16);
    }
    ushort_t* dst = attout + ((size_t)(bb * TSEQ + qb * 64 + r)) * CC + hh * DH + qc * 16;
    ((uint4*)dst)[0] = make_uint4(wb[0], wb[1], wb[2], wb[3]);
    ((uint4*)dst)[1] = make_uint4(wb[4], wb[5], wb[6], wb[7]);
}

// ---------------------------------------------------------------------------
extern "C" void kernel_launch(void* const* d_in, const int* in_sizes, int n_in,
                              void* d_out, int out_size, void* d_ws, size_t ws_size,
                              hipStream_t stream)
{
    (void)in_sizes; (void)n_in; (void)out_size; (void)ws_size;
    const float* x     = (const float*)d_in[0];
    const float* ln1_g = (const float*)d_in[1];
    const float* ln1_b = (const float*)d_in[2];
    const float* Wq    = (const float*)d_in[3];
    const float* Wk    = (const float*)d_in[4];
    const float* Wv    = (const float*)d_in[5];
    const float* Wo    = (const float*)d_in[6];
    const float* bo    = (const float*)d_in[7];
    const float* ln2_g = (const float*)d_in[8];
    const float* ln2_b = (const float*)d_in[9];
    const float* W1    = (const float*)d_in[10];
    const float* b1    = (const float*)d_in[11];
    const float* W2    = (const float*)d_in[12];
    const float* b2    = (const float*)d_in[13];

    char* p = (char*)d_ws;
    ushort_t* hbuf  = (ushort_t*)p;  p += (size_t)BT * CC * 2;
    ushort_t* WqkvT = (ushort_t*)p;  p += (size_t)3 * CC * CC * 2;
    ushort_t* WoT   = (ushort_t*)p;  p += (size_t)CC * CC * 2;
    ushort_t* W1T   = (ushort_t*)p;  p += (size_t)CC * HID * 2;
    ushort_t* W2T   = (ushort_t*)p;  p += (size_t)HID * CC * 2;
    ushort_t* Qb    = (ushort_t*)p;  p += (size_t)BT * CC * 2;
    ushort_t* Kbuf  = (ushort_t*)p;  p += (size_t)BT * CC * 2;
    ushort_t* Vt    = (ushort_t*)p;  p += (size_t)BT * CC * 2;
    ushort_t* atto  = (ushort_t*)p;  p += (size_t)BT * CC * 2;
    float*    x1    = (float*)p;     p += (size_t)BT * CC * 4;
    ushort_t* h2    = (ushort_t*)p;  p += (size_t)BT * CC * 2;
    ushort_t* mid   = (ushort_t*)p;  p += (size_t)BT * HID * 2;
    float*    opart = (float*)p;     p += (size_t)4096 * 4096 * 4;   // flash partials / FFN2 bf16 partials
    float*    mlprt = (float*)p;     p += (size_t)4096 * 128 * 4;

    dim3 blk(256);
    transpose_qkv<<<dim3(DH / 32, CC / 32, 3 * NH), blk, 0, stream>>>(Wq, Wk, Wv, WqkvT);
    transpose_cvt<<<dim3(CC / 32, CC / 32, 1), blk, 0, stream>>>(Wo, WoT, CC, CC);
    transpose_cvt<<<dim3(HID / 32, CC / 32, 1), blk, 0, stream>>>(W1, W1T, CC, HID);
    transpose_cvt<<<dim3(CC / 32, HID / 32, 1), blk, 0, stream>>>(W2, W2T, HID, CC);

    ln_kernel<<<dim3(BT), blk, 0, stream>>>(x, ln1_g, ln1_b, hbuf);
    // QKV: 4096 x 3072 x 1024 at 256^2, 4-phase schedule
    gemm256<2><<<dim3(BT / 256, 3072 / 256), dim3(512), 0, stream>>>(
        hbuf, WqkvT, 3072, CC, CC, CC, nullptr, Qb, Kbuf, Vt);
    flash_split<<<dim3(2 * NH, TSEQ / 64, 4), blk, 0, stream>>>(
        Qb, Kbuf, Vt, opart, mlprt, atto);
    flash_combine<<<dim3(2 * NH, TSEQ / 64 - 8), blk, 0, stream>>>(opart, mlprt, atto);
    // out projection + residual -> x1 (f32), 128x64 counted-ring structure
    gemm_tile<128, 64, 4, 1, 2, 4, 0, 3><<<dim3(BT / 128, CC / 64), blk, 0, stream>>>(
        atto, WoT, CC, CC, CC, CC, bo, x, (void*)x1);
    ln_kernel<<<dim3(BT), blk, 0, stream>>>(x1, ln2_g, ln2_b, h2);
    // FFN1: relu(h2 @ W1 + b1) -> mid, 256^2 4-phase
    gemm256<1><<<dim3(BT / 256, HID / 256), dim3(512), 0, stream>>>(
        h2, W1T, HID, CC, CC, CC, b1, (void*)mid, nullptr, nullptr);
    // FFN2: split-K 4 planes of K=1024 -> bf16 partials, 256^2 4-phase
    gemm256<3><<<dim3(BT / 256, CC / 256, 4), dim3(512), 0, stream>>>(
        mid, W2T, CC, HID / 4, HID, HID, nullptr, (void*)opart, nullptr, nullptr);
    ffn2_combine<<<dim3(BT * CC / 8 / 256), blk, 0, stream>>>(
        (const ushort_t*)opart, b2, x1, (float*)d_out);
}

// Round 14
// 274.430 us; speedup vs baseline: 1.0549x; 1.0549x over previous
//
#include <hip/hip_runtime.h>

typedef unsigned short ushort_t;
typedef __attribute__((ext_vector_type(8))) short short8;
typedef __attribute__((ext_vector_type(4))) float f32x4;

#define BT 4096
#define TSEQ 2048
#define CC 1024
#define NH 16
#define DH 64
#define HID 4096
#define ATT_SCALE 0.03125f   /* C^-0.5 = 1/32 (reference scales by C, not DH) */

__device__ __forceinline__ ushort_t f2bf(float f) {
    unsigned u = __float_as_uint(f);
    u = u + 0x7fffu + ((u >> 16) & 1u);
    return (ushort_t)(u >> 16);
}
__device__ __forceinline__ float bf2f(ushort_t u) {
    return __uint_as_float(((unsigned)u) << 16);
}

typedef const __attribute__((address_space(1))) unsigned int* gptr_t;
typedef __attribute__((address_space(3))) unsigned int* lptr_t;
__device__ __forceinline__ void gload_lds16(const void* g, void* l) {
    __builtin_amdgcn_global_load_lds((gptr_t)g, (lptr_t)l, 16, 0, 0);
}

template <int N> __device__ __forceinline__ void vmcnt_wait() {
    if constexpr (N == 0)      asm volatile("s_waitcnt vmcnt(0)" ::: "memory");
    else if constexpr (N == 3) asm volatile("s_waitcnt vmcnt(3)" ::: "memory");
    else if constexpr (N == 4) asm volatile("s_waitcnt vmcnt(4)" ::: "memory");
    else if constexpr (N == 6) asm volatile("s_waitcnt vmcnt(6)" ::: "memory");
    else static_assert(N == 0, "unsupported vmcnt");
}

// XCD-aware bijective block swizzle (requires gridDim.x*gridDim.y % 8 == 0):
// consecutive swizzled ids within an XCD share the B-panel -> L2 reuse.
__device__ __forceinline__ void xcd_swz(int& bx, int& by) {
    const int nx = gridDim.x;
    const int nwg = nx * gridDim.y;
    const int flat = by * nx + bx;
    const int q = nwg >> 3;
    const int id = (flat & 7) * q + (flat >> 3);
    bx = id % nx;
    by = id / nx;
}

// ---------------------------------------------------------------------------
// Tiled transpose + f32->bf16 convert:  in [R][Cn] f32  ->  out [Cn][R] bf16
// ---------------------------------------------------------------------------
__global__ __launch_bounds__(256) void transpose_cvt(
    const float* __restrict__ in, ushort_t* __restrict__ out, int R, int Cn)
{
    __shared__ float tile[32][33];
    size_t off = (size_t)blockIdx.z * R * Cn;
    int c0 = blockIdx.x * 32, r0 = blockIdx.y * 32;
    int tx = threadIdx.x & 31, ty = threadIdx.x >> 5;
#pragma unroll
    for (int q = 0; q < 4; ++q)
        tile[ty + 8 * q][tx] = in[off + (size_t)(r0 + ty + 8 * q) * Cn + c0 + tx];
    __syncthreads();
#pragma unroll
    for (int q = 0; q < 4; ++q)
        out[off + (size_t)(c0 + ty + 8 * q) * R + r0 + tx] = f2bf(tile[tx][ty + 8 * q]);
}

// QKV weight transpose, merged: z = mat*16 + head; [C][64] -> [64][C] per head
__global__ __launch_bounds__(256) void transpose_qkv(
    const float* __restrict__ Wq, const float* __restrict__ Wk,
    const float* __restrict__ Wv, ushort_t* __restrict__ WqkvT)
{
    __shared__ float tile[32][33];
    int z = blockIdx.z, mat = z >> 4, head = z & 15;
    const float* in = (mat == 0 ? Wq : (mat == 1 ? Wk : Wv)) + (size_t)head * CC * DH;
    ushort_t* out = WqkvT + (size_t)z * DH * CC;
    int c0 = blockIdx.x * 32, r0 = blockIdx.y * 32;
    int tx = threadIdx.x & 31, ty = threadIdx.x >> 5;
#pragma unroll
    for (int q = 0; q < 4; ++q)
        tile[ty + 8 * q][tx] = in[(size_t)(r0 + ty + 8 * q) * DH + c0 + tx];
    __syncthreads();
#pragma unroll
    for (int q = 0; q < 4; ++q)
        out[(size_t)(c0 + ty + 8 * q) * CC + r0 + tx] = f2bf(tile[tx][ty + 8 * q]);
}

// ---------------------------------------------------------------------------
// LayerNorm row kernel: x f32 [rows][1024] -> out bf16.
// ---------------------------------------------------------------------------
__global__ __launch_bounds__(256) void ln_kernel(
    const float* __restrict__ x, const float* __restrict__ g,
    const float* __restrict__ b, ushort_t* __restrict__ out)
{
    int row = blockIdx.x;
    const float4 xv = ((const float4*)(x + (size_t)row * CC))[threadIdx.x];
    float s = xv.x + xv.y + xv.z + xv.w;
    float s2 = xv.x * xv.x + xv.y * xv.y + xv.z * xv.z + xv.w * xv.w;
#pragma unroll
    for (int d = 1; d < 64; d <<= 1) {
        s += __shfl_xor(s, d);
        s2 += __shfl_xor(s2, d);
    }
    __shared__ float ps[4], ps2[4];
    int w = threadIdx.x >> 6, lane = threadIdx.x & 63;
    if (lane == 0) { ps[w] = s; ps2[w] = s2; }
    __syncthreads();
    s = ps[0] + ps[1] + ps[2] + ps[3];
    s2 = ps2[0] + ps2[1] + ps2[2] + ps2[3];
    float mu = s * (1.0f / CC);
    float var = s2 * (1.0f / CC) - mu * mu;
    float rs = rsqrtf(var + 1e-5f);
    int c = threadIdx.x * 4;
    const float4 gv = ((const float4*)g)[threadIdx.x];
    const float4 bv = ((const float4*)b)[threadIdx.x];
    ushort_t u0 = f2bf((xv.x - mu) * rs * gv.x + bv.x);
    ushort_t u1 = f2bf((xv.y - mu) * rs * gv.y + bv.y);
    ushort_t u2 = f2bf((xv.z - mu) * rs * gv.z + bv.z);
    ushort_t u3 = f2bf((xv.w - mu) * rs * gv.w + bv.w);
    unsigned lo = (unsigned)u0 | ((unsigned)u1 << 16);
    unsigned hi = (unsigned)u2 | ((unsigned)u3 << 16);
    ((uint2*)(out + (size_t)row * CC + c))[0] = make_uint2(lo, hi);
}

// ---------------------------------------------------------------------------
// LDS-staged NT GEMM, depth-D ring buffer with COUNTED vmcnt + XCD swizzle:
// prologue stages D-1 tiles; step t stages tile t+D-1 into the freed buffer,
// then waits vmcnt((D-1)*L) -> only tile t certified, D-1 tiles in flight.
// MODE 0: f32 out = acc + bias[n] + resid[m][n]
// MODE 1: bf16 out = relu(acc + bias[n])
// MODE 2: QKV scatter (Q prescaled by ATT_SCALE)
// MODE 3: split-K bf16 partial at plane blockIdx.z (A/B column offset z*K)
// ---------------------------------------------------------------------------
template <int BM, int BN, int WM, int WN, int MR, int NR, int MODE, int D>
__global__ __launch_bounds__(256) void gemm_tile(
    const ushort_t* __restrict__ A, const ushort_t* __restrict__ Bt,
    int N, int K, int lda, int ldb,
    const float* __restrict__ bias, const float* __restrict__ resid,
    void* __restrict__ out0, void* __restrict__ out1, void* __restrict__ out2)
{
    static_assert(WM * WN == 4 && WM * MR * 16 == BM && WN * NR * 16 == BN, "geom");
    constexpr int L = BM / 64 + BN / 64;
    __shared__ ushort_t As[D][BM * 32];
    __shared__ ushort_t Bs[D][BN * 32];

    const int t = threadIdx.x;
    const int w = t >> 6, lane = t & 63, g = lane >> 4, c = lane & 15;
    const int wr = w / WN, wc = w % WN;
    int bx = blockIdx.x, by = blockIdx.y;
    xcd_swz(bx, by);
    const int m0 = bx * BM;
    const int n0 = by * BN;
    if (MODE == 3) {   // K-chunk column offset
        A += (size_t)blockIdx.z * K;
        Bt += (size_t)blockIdx.z * K;
    }

    f32x4 acc[MR][NR];
#pragma unroll
    for (int mi = 0; mi < MR; ++mi)
#pragma unroll
        for (int ni = 0; ni < NR; ++ni) acc[mi][ni] = f32x4{0.f, 0.f, 0.f, 0.f};

    const int arow = t >> 2, acol = (t & 3) * 8;
    const int aoff = (wr * MR * 16 + c) * 32 + g * 8;
    const int boff = (wc * NR * 16 + c) * 32 + g * 8;

#define STAGE(BUF, K0)                                                          \
    {                                                                           \
        _Pragma("unroll") for (int j = 0; j < BM / 64; ++j)                     \
            gload_lds16(A + (size_t)(m0 + j * 64 + arow) * lda + (K0) + acol,   \
                        As[BUF] + (size_t)j * 2048 + t * 8);                    \
        _Pragma("unroll") for (int j = 0; j < BN / 64; ++j)                     \
            gload_lds16(Bt + (size_t)(n0 + j * 64 + arow) * ldb + (K0) + acol,  \
                        Bs[BUF] + (size_t)j * 2048 + t * 8);                    \
    }

    const int nt = K >> 5;
#pragma unroll
    for (int d = 0; d < D - 1; ++d) STAGE(d, d * 32);

    int cur = 0;
    for (int ti = 0; ti < nt; ++ti) {
        const int ahead = nt - 1 - ti;
        if (ahead >= D - 1) {
            const int stg = (cur == 0) ? D - 1 : cur - 1;
            STAGE(stg, (ti + D - 1) * 32);
            vmcnt_wait<(D - 1) * L>();
        } else if (D == 3 && ahead == 1) {
            vmcnt_wait<L>();
        } else {
            vmcnt_wait<0>();
        }
        __builtin_amdgcn_sched_barrier(0);
        __builtin_amdgcn_s_barrier();

        const ushort_t* Ard = As[cur] + aoff;
        const ushort_t* Brd = Bs[cur] + boff;
        short8 af[MR], bf[NR];
#pragma unroll
        for (int mi = 0; mi < MR; ++mi) af[mi] = *(const short8*)(Ard + mi * 512);
#pragma unroll
        for (int ni = 0; ni < NR; ++ni) bf[ni] = *(const short8*)(Brd + ni * 512);
        __builtin_amdgcn_s_setprio(1);
#pragma unroll
        for (int mi = 0; mi < MR; ++mi)
#pragma unroll
            for (int ni = 0; ni < NR; ++ni)
                acc[mi][ni] = __builtin_amdgcn_mfma_f32_16x16x32_bf16(
                    af[mi], bf[ni], acc[mi][ni], 0, 0, 0);
        __builtin_amdgcn_s_setprio(0);

        __builtin_amdgcn_sched_barrier(0);
        __builtin_amdgcn_s_barrier();
        cur = (cur + 1 == D) ? 0 : cur + 1;
    }
#undef STAGE

#pragma unroll
    for (int mi = 0; mi < MR; ++mi)
#pragma unroll
        for (int ni = 0; ni < NR; ++ni)
#pragma unroll
            for (int i = 0; i < 4; ++i) {
                int row = m0 + wr * MR * 16 + mi * 16 + g * 4 + i;
                int col = n0 + wc * NR * 16 + ni * 16 + c;
                float v = acc[mi][ni][i];
                if (MODE == 0) {
                    v += bias[col] + resid[(size_t)row * N + col];
                    ((float*)out0)[(size_t)row * N + col] = v;
                } else if (MODE == 1) {
                    v += bias[col];
                    v = v > 0.f ? v : 0.f;
                    ((ushort_t*)out0)[(size_t)row * N + col] = f2bf(v);
                } else if (MODE == 3) {
                    ((ushort_t*)out0)[(size_t)blockIdx.z * BT * N + (size_t)row * N + col] =
                        f2bf(v);
                } else {
                    int bb = row >> 11, tt = row & (TSEQ - 1);
                    if (col < 1024) {
                        int head = col >> 6, d = col & 63;
                        ((ushort_t*)out0)[((size_t)(bb * NH + head) * TSEQ + tt) * DH + d] =
                            f2bf(v * ATT_SCALE);
                    } else if (col < 2048) {
                        int head = (col - 1024) >> 6, d = col & 63;
                        ((ushort_t*)out1)[((size_t)(bb * NH + head) * TSEQ + tt) * DH + d] = f2bf(v);
                    } else {
                        int head = (col - 2048) >> 6, d = col & 63;
                        ((ushort_t*)out2)[((size_t)(bb * NH + head) * DH + d) * TSEQ + tt] = f2bf(v);
                    }
                }
            }
}

// ---------------------------------------------------------------------------
// FFN2 combine: out[m][n] = sum_{z<2} bf16 parts[z][m][n] + bias[n] + resid
// ---------------------------------------------------------------------------
__global__ __launch_bounds__(256) void ffn2_combine(
    const ushort_t* __restrict__ parts, const float* __restrict__ bias,
    const float* __restrict__ resid, float* __restrict__ out)
{
    const size_t off = ((size_t)blockIdx.x * 256 + threadIdx.x) * 8;
    const int col = (int)(off & 1023);
    short8 p0 = *(const short8*)(parts + off);
    short8 p1 = *(const short8*)(parts + (size_t)BT * CC + off);
    float4 r0 = ((const float4*)(resid + off))[0];
    float4 r1 = ((const float4*)(resid + off + 4))[0];
    float4 b0 = ((const float4*)(bias + col))[0];
    float4 b1 = ((const float4*)(bias + col + 4))[0];
    float o[8];
#pragma unroll
    for (int j = 0; j < 8; ++j)
        o[j] = bf2f((ushort_t)p0[j]) + bf2f((ushort_t)p1[j]);
    float4 w0 = make_float4(o[0] + b0.x + r0.x, o[1] + b0.y + r0.y,
                            o[2] + b0.z + r0.z, o[3] + b0.w + r0.w);
    float4 w1 = make_float4(o[4] + b1.x + r1.x, o[5] + b1.y + r1.y,
                            o[6] + b1.z + r1.z, o[7] + b1.w + r1.w);
    ((float4*)(out + off))[0] = w0;
    ((float4*)(out + off + 4))[0] = w1;
}

// ---------------------------------------------------------------------------
// Split flash: K/V tiles staged per block into LDS (global_load_lds,
// inverse-swizzled source), shared by 4 waves.  grid (B*H, T/64, 4 chunks).
// ---------------------------------------------------------------------------
__global__ __launch_bounds__(256) void flash_split(
    const ushort_t* __restrict__ Q, const ushort_t* __restrict__ Kb,
    const ushort_t* __restrict__ Vt, float* __restrict__ opart,
    float* __restrict__ mlpart, ushort_t* __restrict__ attout)
{
    __shared__ ushort_t Ks[64 * 64];
    __shared__ ushort_t Vs[64 * 64];
    __shared__ ushort_t Plds[4][16 * 72];
    const int t = threadIdx.x;
    const int w = t >> 6, lane = t & 63;
    const int g = lane >> 4, c = lane & 15;
    const int bh = blockIdx.x, qb = blockIdx.y, sc = blockIdx.z;
    if (sc * 8 > qb) return;
    const int bb = bh >> 4, hh = bh & 15;
    const int q0 = qb * 64 + w * 16;
    const ushort_t* qp = Q + (size_t)bh * TSEQ * DH;
    const char* kpB = (const char*)(Kb + (size_t)bh * TSEQ * DH);
    const char* vpB = (const char*)(Vt + (size_t)bh * DH * TSEQ);

    const short8 bq0 = *(const short8*)(qp + (size_t)(q0 + c) * DH + g * 8);
    const short8 bq1 = *(const short8*)(qp + (size_t)(q0 + c) * DH + 32 + g * 8);

    float m_ = -INFINITY, l_ = 0.f;
    f32x4 o[4];
#pragma unroll
    for (int nf = 0; nf < 4; ++nf) o[nf] = f32x4{0.f, 0.f, 0.f, 0.f};

    const int st0 = sc * 8;
    const int send = (st0 + 7 < qb) ? st0 + 7 : qb;
    ushort_t* pw = &Plds[w][c * 72];
    const unsigned bxor = (unsigned)((c & 7) << 4);

    const int srow = t >> 3, sb = (t & 7) * 16;
#define STAGE_KV(ST)                                                                \
    {                                                                               \
        const int S0_ = (ST) * 64;                                                  \
        _Pragma("unroll") for (int j = 0; j < 2; ++j) {                             \
            int r = j * 32 + srow;                                                  \
            int bs = sb ^ ((r & 7) << 4);                                           \
            gload_lds16(kpB + (size_t)(S0_ + r) * 128 + bs,                         \
                        (char*)Ks + r * 128 + sb);                                  \
            gload_lds16(vpB + (size_t)r * (TSEQ * 2) + S0_ * 2 + bs,                \
                        (char*)Vs + r * 128 + sb);                                  \
        }                                                                           \
    }

    STAGE_KV(st0);
    for (int st = st0; st <= send; ++st) {
        const int S0 = st * 64;
        __syncthreads();

        __builtin_amdgcn_s_setprio(1);
        f32x4 sa[4];
#pragma unroll
        for (int sub = 0; sub < 4; ++sub) {
            const char* kr = (const char*)Ks + (16 * sub + c) * 128;
            short8 k0 = *(const short8*)(kr + ((g * 16) ^ bxor));
            short8 k1 = *(const short8*)(kr + ((64 + g * 16) ^ bxor));
            f32x4 t0 = f32x4{0.f, 0.f, 0.f, 0.f};
            t0 = __builtin_amdgcn_mfma_f32_16x16x32_bf16(k0, bq0, t0, 0, 0, 0);
            t0 = __builtin_amdgcn_mfma_f32_16x16x32_bf16(k1, bq1, t0, 0, 0, 0);
            sa[sub] = t0;
        }
        __builtin_amdgcn_s_setprio(0);

        float pvv[16];
#pragma unroll
        for (int sub = 0; sub < 4; ++sub)
#pragma unroll
            for (int i = 0; i < 4; ++i) pvv[4 * sub + i] = sa[sub][i];
        if (st == qb) {
#pragma unroll
            for (int sub = 0; sub < 4; ++sub)
#pragma unroll
                for (int i = 0; i < 4; ++i)
                    if (S0 + 16 * sub + 4 * g + i > q0 + c) pvv[4 * sub + i] = -INFINITY;
        }
        float tmax = pvv[0];
#pragma unroll
        for (int j = 1; j < 16; ++j) tmax = fmaxf(tmax, pvv[j]);
        tmax = fmaxf(tmax, __shfl_xor(tmax, 16));
        tmax = fmaxf(tmax, __shfl_xor(tmax, 32));
        if (!__all(tmax - m_ <= 8.0f)) {
            float mn = fmaxf(m_, tmax);
            float fac = __expf(m_ - mn);
            m_ = mn;
            l_ *= fac;
#pragma unroll
            for (int i = 0; i < 4; ++i) {
                float fr = __shfl(fac, 4 * g + i);
#pragma unroll
                for (int nf = 0; nf < 4; ++nf) o[nf][i] *= fr;
            }
        }
        float pp[16], rs = 0.f;
#pragma unroll
        for (int j = 0; j < 16; ++j) { pp[j] = __expf(pvv[j] - m_); rs += pp[j]; }
        rs += __shfl_xor(rs, 16);
        rs += __shfl_xor(rs, 32);
        l_ += rs;

#pragma unroll
        for (int sub = 0; sub < 4; ++sub) {
            unsigned lo = (__float_as_uint(pp[4 * sub + 0]) >> 16) |
                          (__float_as_uint(pp[4 * sub + 1]) & 0xffff0000u);
            unsigned hi = (__float_as_uint(pp[4 * sub + 2]) >> 16) |
                          (__float_as_uint(pp[4 * sub + 3]) & 0xffff0000u);
            *(uint2*)(pw + 16 * sub + 4 * g) = make_uint2(lo, hi);
        }
        asm volatile("s_waitcnt lgkmcnt(0)" ::: "memory");
        short8 pa0 = *(const short8*)(&Plds[w][c * 72 + g * 8]);
        short8 pa1 = *(const short8*)(&Plds[w][c * 72 + 32 + g * 8]);

        __builtin_amdgcn_s_setprio(1);
#pragma unroll
        for (int nf = 0; nf < 4; ++nf) {
            const char* vr = (const char*)Vs + (nf * 16 + c) * 128;
            short8 v0 = *(const short8*)(vr + ((g * 16) ^ bxor));
            short8 v1 = *(const short8*)(vr + ((64 + g * 16) ^ bxor));
            o[nf] = __builtin_amdgcn_mfma_f32_16x16x32_bf16(pa0, v0, o[nf], 0, 0, 0);
            o[nf] = __builtin_amdgcn_mfma_f32_16x16x32_bf16(pa1, v1, o[nf], 0, 0, 0);
        }
        __builtin_amdgcn_s_setprio(0);

        __syncthreads();
        if (st < send) STAGE_KV(st + 1);
    }
#undef STAGE_KV

    if (qb < 8) {
#pragma unroll
        for (int i = 0; i < 4; ++i) {
            float rl = 1.0f / __shfl(l_, 4 * g + i);
            int tt = q0 + 4 * g + i;
#pragma unroll
            for (int nf = 0; nf < 4; ++nf)
                attout[((size_t)(bb * TSEQ + tt)) * CC + hh * DH + nf * 16 + c] =
                    f2bf(o[nf][i] * rl);
        }
    } else {
        const size_t slot = (size_t)(bh * 32 + qb) * 4 + sc;
        float* op = opart + slot * 4096;
#pragma unroll
        for (int nf = 0; nf < 4; ++nf)
#pragma unroll
            for (int i = 0; i < 4; ++i)
                op[(size_t)(w * 16 + 4 * g + i) * 64 + nf * 16 + c] = o[nf][i];
        if (g == 0) {
            mlpart[slot * 128 + w * 16 + c] = m_;
            mlpart[slot * 128 + 64 + w * 16 + c] = l_;
        }
    }
}

// ---------------------------------------------------------------------------
// Combine partials for qb >= 8.  grid (B*H, 24) -> qb = blockIdx.y + 8.
// ---------------------------------------------------------------------------
__global__ __launch_bounds__(256) void flash_combine(
    const float* __restrict__ opart, const float* __restrict__ mlpart,
    ushort_t* __restrict__ attout)
{
    const int bh = blockIdx.x, qb = blockIdx.y + 8;
    const int bb = bh >> 4, hh = bh & 15;
    const int nsc = (qb >> 3) + 1;
    const int t = threadIdx.x, r = t >> 2, qc = t & 3;
    const size_t slot0 = (size_t)(bh * 32 + qb) * 4;

    float mi[4], li[4];
    float M = -INFINITY;
#pragma unroll
    for (int i = 0; i < 4; ++i) {
        if (i < nsc) {
            mi[i] = mlpart[(slot0 + i) * 128 + r];
            li[i] = mlpart[(slot0 + i) * 128 + 64 + r];
            M = fmaxf(M, mi[i]);
        }
    }
    float L = 0.f;
    f32x4 acc[4];
#pragma unroll
    for (int j = 0; j < 4; ++j) acc[j] = f32x4{0.f, 0.f, 0.f, 0.f};
#pragma unroll
    for (int i = 0; i < 4; ++i) {
        if (i < nsc) {
            float F = __expf(mi[i] - M);
            L += li[i] * F;
            const f32x4* orow = (const f32x4*)(opart + (slot0 + i) * 4096 +
                                               (size_t)r * 64 + qc * 16);
#pragma unroll
            for (int j = 0; j < 4; ++j) acc[j] += orow[j] * F;
        }
    }
    float rl = 1.0f / L;
    unsigned wb[8];
#pragma unroll
    for (int j = 0; j < 4; ++j) {
        wb[2 * j] = (unsigned)f2bf(acc[j][0] * rl) | ((unsigned)f2bf(acc[j][1] * rl) << 16);
        wb[2 * j + 1] = (unsigned)f2bf(acc[j][2] * rl) | ((unsigned)f2bf(acc[j][3] * rl) << 16);
    }
    ushort_t* dst = attout + ((size_t)(bb * TSEQ + qb * 64 + r)) * CC + hh * DH + qc * 16;
    ((uint4*)dst)[0] = make_uint4(wb[0], wb[1], wb[2], wb[3]);
    ((uint4*)dst)[1] = make_uint4(wb[4], wb[5], wb[6], wb[7]);
}

// ---------------------------------------------------------------------------
extern "C" void kernel_launch(void* const* d_in, const int* in_sizes, int n_in,
                              void* d_out, int out_size, void* d_ws, size_t ws_size,
                              hipStream_t stream)
{
    (void)in_sizes; (void)n_in; (void)out_size; (void)ws_size;
    const float* x     = (const float*)d_in[0];
    const float* ln1_g = (const float*)d_in[1];
    const float* ln1_b = (const float*)d_in[2];
    const float* Wq    = (const float*)d_in[3];
    const float* Wk    = (const float*)d_in[4];
    const float* Wv    = (const float*)d_in[5];
    const float* Wo    = (const float*)d_in[6];
    const float* bo    = (const float*)d_in[7];
    const float* ln2_g = (const float*)d_in[8];
    const float* ln2_b = (const float*)d_in[9];
    const float* W1    = (const float*)d_in[10];
    const float* b1    = (const float*)d_in[11];
    const float* W2    = (const float*)d_in[12];
    const float* b2    = (const float*)d_in[13];

    char* p = (char*)d_ws;
    ushort_t* hbuf  = (ushort_t*)p;  p += (size_t)BT * CC * 2;
    ushort_t* WqkvT = (ushort_t*)p;  p += (size_t)3 * CC * CC * 2;
    ushort_t* WoT   = (ushort_t*)p;  p += (size_t)CC * CC * 2;
    ushort_t* W1T   = (ushort_t*)p;  p += (size_t)CC * HID * 2;
    ushort_t* W2T   = (ushort_t*)p;  p += (size_t)HID * CC * 2;
    ushort_t* Qb    = (ushort_t*)p;  p += (size_t)BT * CC * 2;
    ushort_t* Kbuf  = (ushort_t*)p;  p += (size_t)BT * CC * 2;
    ushort_t* Vt    = (ushort_t*)p;  p += (size_t)BT * CC * 2;
    ushort_t* atto  = (ushort_t*)p;  p += (size_t)BT * CC * 2;
    float*    x1    = (float*)p;     p += (size_t)BT * CC * 4;
    ushort_t* h2    = (ushort_t*)p;  p += (size_t)BT * CC * 2;
    ushort_t* mid   = (ushort_t*)p;  p += (size_t)BT * HID * 2;
    float*    opart = (float*)p;     p += (size_t)4096 * 4096 * 4;   // flash partials / FFN2 bf16 partials
    float*    mlprt = (float*)p;     p += (size_t)4096 * 128 * 4;

    dim3 blk(256);
    transpose_qkv<<<dim3(DH / 32, CC / 32, 3 * NH), blk, 0, stream>>>(Wq, Wk, Wv, WqkvT);
    transpose_cvt<<<dim3(CC / 32, CC / 32, 1), blk, 0, stream>>>(Wo, WoT, CC, CC);
    transpose_cvt<<<dim3(HID / 32, CC / 32, 1), blk, 0, stream>>>(W1, W1T, CC, HID);
    transpose_cvt<<<dim3(CC / 32, HID / 32, 1), blk, 0, stream>>>(W2, W2T, HID, CC);

    ln_kernel<<<dim3(BT), blk, 0, stream>>>(x, ln1_g, ln1_b, hbuf);
    // QKV: [4096]x[3072]x[1024], 128^2 D=2, grid 32x24=768 (%8==0)
    gemm_tile<128, 128, 2, 2, 4, 4, 2, 2><<<dim3(BT / 128, 3072 / 128), blk, 0, stream>>>(
        hbuf, WqkvT, 3072, CC, CC, CC, nullptr, nullptr, Qb, Kbuf, Vt);
    flash_split<<<dim3(2 * NH, TSEQ / 64, 4), blk, 0, stream>>>(
        Qb, Kbuf, Vt, opart, mlprt, atto);
    flash_combine<<<dim3(2 * NH, TSEQ / 64 - 8), blk, 0, stream>>>(opart, mlprt, atto);
    // out projection + residual -> x1 (f32), 128x64 D=3, grid 32x16=512
    gemm_tile<128, 64, 4, 1, 2, 4, 0, 3><<<dim3(BT / 128, CC / 64), blk, 0, stream>>>(
        atto, WoT, CC, CC, CC, CC, bo, x, (void*)x1, nullptr, nullptr);
    ln_kernel<<<dim3(BT), blk, 0, stream>>>(x1, ln2_g, ln2_b, h2);
    // FFN1: relu(h2 @ W1 + b1) -> mid, 128^2 D=2, grid 32x32=1024
    gemm_tile<128, 128, 2, 2, 4, 4, 1, 2><<<dim3(BT / 128, HID / 128), blk, 0, stream>>>(
        h2, W1T, HID, CC, CC, CC, b1, nullptr, (void*)mid, nullptr, nullptr);
    // FFN2 split-K: 2 chunks of K=2048 -> bf16 partials, 128x64 D=3, grid 32x16x2
    gemm_tile<128, 64, 4, 1, 2, 4, 3, 3><<<dim3(BT / 128, CC / 64, 2), blk, 0, stream>>>(
        mid, W2T, CC, HID / 2, HID, HID, nullptr, nullptr, (void*)opart, nullptr, nullptr);
    ffn2_combine<<<dim3(BT * CC / 8 / 256), blk, 0, stream>>>(
        (const ushort_t*)opart, b2, x1, (float*)d_out);
}

// Round 15
// 262.256 us; speedup vs baseline: 1.1038x; 1.0464x over previous
//
#include <hip/hip_runtime.h>

typedef unsigned short ushort_t;
typedef __attribute__((ext_vector_type(8))) short short8;
typedef __attribute__((ext_vector_type(4))) float f32x4;

#define BT 4096
#define TSEQ 2048
#define CC 1024
#define NH 16
#define DH 64
#define HID 4096
#define ATT_SCALE 0.03125f   /* C^-0.5 = 1/32 (reference scales by C, not DH) */

__device__ __forceinline__ ushort_t f2bf(float f) {
    unsigned u = __float_as_uint(f);
    u = u + 0x7fffu + ((u >> 16) & 1u);
    return (ushort_t)(u >> 16);
}
__device__ __forceinline__ float bf2f(ushort_t u) {
    return __uint_as_float(((unsigned)u) << 16);
}

typedef const __attribute__((address_space(1))) unsigned int* gptr_t;
typedef __attribute__((address_space(3))) unsigned int* lptr_t;
__device__ __forceinline__ void gload_lds16(const void* g, void* l) {
    __builtin_amdgcn_global_load_lds((gptr_t)g, (lptr_t)l, 16, 0, 0);
}

template <int N> __device__ __forceinline__ void vmcnt_wait() {
    if constexpr (N == 0)      asm volatile("s_waitcnt vmcnt(0)" ::: "memory");
    else if constexpr (N == 3) asm volatile("s_waitcnt vmcnt(3)" ::: "memory");
    else if constexpr (N == 4) asm volatile("s_waitcnt vmcnt(4)" ::: "memory");
    else if constexpr (N == 6) asm volatile("s_waitcnt vmcnt(6)" ::: "memory");
    else static_assert(N == 0, "unsupported vmcnt");
}

// ---------------------------------------------------------------------------
// Tiled transpose + f32->bf16 convert:  in [R][Cn] f32  ->  out [Cn][R] bf16
// ---------------------------------------------------------------------------
__global__ __launch_bounds__(256) void transpose_cvt(
    const float* __restrict__ in, ushort_t* __restrict__ out, int R, int Cn)
{
    __shared__ float tile[32][33];
    size_t off = (size_t)blockIdx.z * R * Cn;
    int c0 = blockIdx.x * 32, r0 = blockIdx.y * 32;
    int tx = threadIdx.x & 31, ty = threadIdx.x >> 5;
#pragma unroll
    for (int q = 0; q < 4; ++q)
        tile[ty + 8 * q][tx] = in[off + (size_t)(r0 + ty + 8 * q) * Cn + c0 + tx];
    __syncthreads();
#pragma unroll
    for (int q = 0; q < 4; ++q)
        out[off + (size_t)(c0 + ty + 8 * q) * R + r0 + tx] = f2bf(tile[tx][ty + 8 * q]);
}

// QKV weight transpose, merged: z = mat*16 + head; [C][64] -> [64][C] per head
__global__ __launch_bounds__(256) void transpose_qkv(
    const float* __restrict__ Wq, const float* __restrict__ Wk,
    const float* __restrict__ Wv, ushort_t* __restrict__ WqkvT)
{
    __shared__ float tile[32][33];
    int z = blockIdx.z, mat = z >> 4, head = z & 15;
    const float* in = (mat == 0 ? Wq : (mat == 1 ? Wk : Wv)) + (size_t)head * CC * DH;
    ushort_t* out = WqkvT + (size_t)z * DH * CC;
    int c0 = blockIdx.x * 32, r0 = blockIdx.y * 32;
    int tx = threadIdx.x & 31, ty = threadIdx.x >> 5;
#pragma unroll
    for (int q = 0; q < 4; ++q)
        tile[ty + 8 * q][tx] = in[(size_t)(r0 + ty + 8 * q) * DH + c0 + tx];
    __syncthreads();
#pragma unroll
    for (int q = 0; q < 4; ++q)
        out[(size_t)(c0 + ty + 8 * q) * CC + r0 + tx] = f2bf(tile[tx][ty + 8 * q]);
}

// ---------------------------------------------------------------------------
// LayerNorm row kernel: x f32 [rows][1024] -> out bf16.
// ---------------------------------------------------------------------------
__global__ __launch_bounds__(256) void ln_kernel(
    const float* __restrict__ x, const float* __restrict__ g,
    const float* __restrict__ b, ushort_t* __restrict__ out)
{
    int row = blockIdx.x;
    const float4 xv = ((const float4*)(x + (size_t)row * CC))[threadIdx.x];
    float s = xv.x + xv.y + xv.z + xv.w;
    float s2 = xv.x * xv.x + xv.y * xv.y + xv.z * xv.z + xv.w * xv.w;
#pragma unroll
    for (int d = 1; d < 64; d <<= 1) {
        s += __shfl_xor(s, d);
        s2 += __shfl_xor(s2, d);
    }
    __shared__ float ps[4], ps2[4];
    int w = threadIdx.x >> 6, lane = threadIdx.x & 63;
    if (lane == 0) { ps[w] = s; ps2[w] = s2; }
    __syncthreads();
    s = ps[0] + ps[1] + ps[2] + ps[3];
    s2 = ps2[0] + ps2[1] + ps2[2] + ps2[3];
    float mu = s * (1.0f / CC);
    float var = s2 * (1.0f / CC) - mu * mu;
    float rs = rsqrtf(var + 1e-5f);
    int c = threadIdx.x * 4;
    const float4 gv = ((const float4*)g)[threadIdx.x];
    const float4 bv = ((const float4*)b)[threadIdx.x];
    ushort_t u0 = f2bf((xv.x - mu) * rs * gv.x + bv.x);
    ushort_t u1 = f2bf((xv.y - mu) * rs * gv.y + bv.y);
    ushort_t u2 = f2bf((xv.z - mu) * rs * gv.z + bv.z);
    ushort_t u3 = f2bf((xv.w - mu) * rs * gv.w + bv.w);
    unsigned lo = (unsigned)u0 | ((unsigned)u1 << 16);
    unsigned hi = (unsigned)u2 | ((unsigned)u3 << 16);
    ((uint2*)(out + (size_t)row * CC + c))[0] = make_uint2(lo, hi);
}

// ---------------------------------------------------------------------------
// LDS-staged NT GEMM, depth-D ring buffer with COUNTED vmcnt (no swizzle —
// default round-robin dispatch gives per-XCD A-tile L2 reuse for our shapes).
// MODE 0: f32 out = acc + bias[n] + resid[m][n]
// MODE 1: bf16 out = relu(acc + bias[n])
// MODE 2: QKV scatter (Q prescaled by ATT_SCALE)
// MODE 3: split-K bf16 partial at plane blockIdx.z (A/B column offset z*K)
// ---------------------------------------------------------------------------
template <int BM, int BN, int WM, int WN, int MR, int NR, int MODE, int D>
__global__ __launch_bounds__(256) void gemm_tile(
    const ushort_t* __restrict__ A, const ushort_t* __restrict__ Bt,
    int N, int K, int lda, int ldb,
    const float* __restrict__ bias, const float* __restrict__ resid,
    void* __restrict__ out0, void* __restrict__ out1, void* __restrict__ out2)
{
    static_assert(WM * WN == 4 && WM * MR * 16 == BM && WN * NR * 16 == BN, "geom");
    constexpr int L = BM / 64 + BN / 64;
    __shared__ ushort_t As[D][BM * 32];
    __shared__ ushort_t Bs[D][BN * 32];

    const int t = threadIdx.x;
    const int w = t >> 6, lane = t & 63, g = lane >> 4, c = lane & 15;
    const int wr = w / WN, wc = w % WN;
    const int m0 = blockIdx.x * BM;
    const int n0 = blockIdx.y * BN;
    if (MODE == 3) {   // K-chunk column offset
        A += (size_t)blockIdx.z * K;
        Bt += (size_t)blockIdx.z * K;
    }

    f32x4 acc[MR][NR];
#pragma unroll
    for (int mi = 0; mi < MR; ++mi)
#pragma unroll
        for (int ni = 0; ni < NR; ++ni) acc[mi][ni] = f32x4{0.f, 0.f, 0.f, 0.f};

    const int arow = t >> 2, acol = (t & 3) * 8;
    const int aoff = (wr * MR * 16 + c) * 32 + g * 8;
    const int boff = (wc * NR * 16 + c) * 32 + g * 8;

#define STAGE(BUF, K0)                                                          \
    {                                                                           \
        _Pragma("unroll") for (int j = 0; j < BM / 64; ++j)                     \
            gload_lds16(A + (size_t)(m0 + j * 64 + arow) * lda + (K0) + acol,   \
                        As[BUF] + (size_t)j * 2048 + t * 8);                    \
        _Pragma("unroll") for (int j = 0; j < BN / 64; ++j)                     \
            gload_lds16(Bt + (size_t)(n0 + j * 64 + arow) * ldb + (K0) + acol,  \
                        Bs[BUF] + (size_t)j * 2048 + t * 8);                    \
    }

    const int nt = K >> 5;
#pragma unroll
    for (int d = 0; d < D - 1; ++d) STAGE(d, d * 32);

    int cur = 0;
    for (int ti = 0; ti < nt; ++ti) {
        const int ahead = nt - 1 - ti;
        if (ahead >= D - 1) {
            const int stg = (cur == 0) ? D - 1 : cur - 1;
            STAGE(stg, (ti + D - 1) * 32);
            vmcnt_wait<(D - 1) * L>();
        } else if (D == 3 && ahead == 1) {
            vmcnt_wait<L>();
        } else {
            vmcnt_wait<0>();
        }
        __builtin_amdgcn_sched_barrier(0);
        __builtin_amdgcn_s_barrier();

        const ushort_t* Ard = As[cur] + aoff;
        const ushort_t* Brd = Bs[cur] + boff;
        short8 af[MR], bf[NR];
#pragma unroll
        for (int mi = 0; mi < MR; ++mi) af[mi] = *(const short8*)(Ard + mi * 512);
#pragma unroll
        for (int ni = 0; ni < NR; ++ni) bf[ni] = *(const short8*)(Brd + ni * 512);
        __builtin_amdgcn_s_setprio(1);
#pragma unroll
        for (int mi = 0; mi < MR; ++mi)
#pragma unroll
            for (int ni = 0; ni < NR; ++ni)
                acc[mi][ni] = __builtin_amdgcn_mfma_f32_16x16x32_bf16(
                    af[mi], bf[ni], acc[mi][ni], 0, 0, 0);
        __builtin_amdgcn_s_setprio(0);

        __builtin_amdgcn_sched_barrier(0);
        __builtin_amdgcn_s_barrier();
        cur = (cur + 1 == D) ? 0 : cur + 1;
    }
#undef STAGE

#pragma unroll
    for (int mi = 0; mi < MR; ++mi)
#pragma unroll
        for (int ni = 0; ni < NR; ++ni)
#pragma unroll
            for (int i = 0; i < 4; ++i) {
                int row = m0 + wr * MR * 16 + mi * 16 + g * 4 + i;
                int col = n0 + wc * NR * 16 + ni * 16 + c;
                float v = acc[mi][ni][i];
                if (MODE == 0) {
                    v += bias[col] + resid[(size_t)row * N + col];
                    ((float*)out0)[(size_t)row * N + col] = v;
                } else if (MODE == 1) {
                    v += bias[col];
                    v = v > 0.f ? v : 0.f;
                    ((ushort_t*)out0)[(size_t)row * N + col] = f2bf(v);
                } else if (MODE == 3) {
                    ((ushort_t*)out0)[(size_t)blockIdx.z * BT * N + (size_t)row * N + col] =
                        f2bf(v);
                } else {
                    int bb = row >> 11, tt = row & (TSEQ - 1);
                    if (col < 1024) {
                        int head = col >> 6, d = col & 63;
                        ((ushort_t*)out0)[((size_t)(bb * NH + head) * TSEQ + tt) * DH + d] =
                            f2bf(v * ATT_SCALE);
                    } else if (col < 2048) {
                        int head = (col - 1024) >> 6, d = col & 63;
                        ((ushort_t*)out1)[((size_t)(bb * NH + head) * TSEQ + tt) * DH + d] = f2bf(v);
                    } else {
                        int head = (col - 2048) >> 6, d = col & 63;
                        ((ushort_t*)out2)[((size_t)(bb * NH + head) * DH + d) * TSEQ + tt] = f2bf(v);
                    }
                }
            }
}

// ---------------------------------------------------------------------------
// FFN2 combine: out[m][n] = sum_{z<4} bf16 parts[z][m][n] + bias[n] + resid
// ---------------------------------------------------------------------------
__global__ __launch_bounds__(256) void ffn2_combine(
    const ushort_t* __restrict__ parts, const float* __restrict__ bias,
    const float* __restrict__ resid, float* __restrict__ out)
{
    const size_t off = ((size_t)blockIdx.x * 256 + threadIdx.x) * 8;
    const int col = (int)(off & 1023);
    short8 p0 = *(const short8*)(parts + off);
    short8 p1 = *(const short8*)(parts + (size_t)BT * CC + off);
    short8 p2 = *(const short8*)(parts + (size_t)2 * BT * CC + off);
    short8 p3 = *(const short8*)(parts + (size_t)3 * BT * CC + off);
    float4 r0 = ((const float4*)(resid + off))[0];
    float4 r1 = ((const float4*)(resid + off + 4))[0];
    float4 b0 = ((const float4*)(bias + col))[0];
    float4 b1 = ((const float4*)(bias + col + 4))[0];
    float o[8];
#pragma unroll
    for (int j = 0; j < 8; ++j)
        o[j] = bf2f((ushort_t)p0[j]) + bf2f((ushort_t)p1[j]) +
               bf2f((ushort_t)p2[j]) + bf2f((ushort_t)p3[j]);
    float4 w0 = make_float4(o[0] + b0.x + r0.x, o[1] + b0.y + r0.y,
                            o[2] + b0.z + r0.z, o[3] + b0.w + r0.w);
    float4 w1 = make_float4(o[4] + b1.x + r1.x, o[5] + b1.y + r1.y,
                            o[6] + b1.z + r1.z, o[7] + b1.w + r1.w);
    ((float4*)(out + off))[0] = w0;
    ((float4*)(out + off + 4))[0] = w1;
}

// ---------------------------------------------------------------------------
// Split flash: K/V tiles staged per block into LDS (global_load_lds,
// inverse-swizzled source), shared by 4 waves.  grid (B*H, T/64, 4 chunks).
// ---------------------------------------------------------------------------
__global__ __launch_bounds__(256) void flash_split(
    const ushort_t* __restrict__ Q, const ushort_t* __restrict__ Kb,
    const ushort_t* __restrict__ Vt, float* __restrict__ opart,
    float* __restrict__ mlpart, ushort_t* __restrict__ attout)
{
    __shared__ ushort_t Ks[64 * 64];
    __shared__ ushort_t Vs[64 * 64];
    __shared__ ushort_t Plds[4][16 * 72];
    const int t = threadIdx.x;
    const int w = t >> 6, lane = t & 63;
    const int g = lane >> 4, c = lane & 15;
    const int bh = blockIdx.x, qb = blockIdx.y, sc = blockIdx.z;
    if (sc * 8 > qb) return;
    const int bb = bh >> 4, hh = bh & 15;
    const int q0 = qb * 64 + w * 16;
    const ushort_t* qp = Q + (size_t)bh * TSEQ * DH;
    const char* kpB = (const char*)(Kb + (size_t)bh * TSEQ * DH);
    const char* vpB = (const char*)(Vt + (size_t)bh * DH * TSEQ);

    const short8 bq0 = *(const short8*)(qp + (size_t)(q0 + c) * DH + g * 8);
    const short8 bq1 = *(const short8*)(qp + (size_t)(q0 + c) * DH + 32 + g * 8);

    float m_ = -INFINITY, l_ = 0.f;
    f32x4 o[4];
#pragma unroll
    for (int nf = 0; nf < 4; ++nf) o[nf] = f32x4{0.f, 0.f, 0.f, 0.f};

    const int st0 = sc * 8;
    const int send = (st0 + 7 < qb) ? st0 + 7 : qb;
    ushort_t* pw = &Plds[w][c * 72];
    const unsigned bxor = (unsigned)((c & 7) << 4);

    const int srow = t >> 3, sb = (t & 7) * 16;
#define STAGE_KV(ST)                                                                \
    {                                                                               \
        const int S0_ = (ST) * 64;                                                  \
        _Pragma("unroll") for (int j = 0; j < 2; ++j) {                             \
            int r = j * 32 + srow;                                                  \
            int bs = sb ^ ((r & 7) << 4);                                           \
            gload_lds16(kpB + (size_t)(S0_ + r) * 128 + bs,                         \
                        (char*)Ks + r * 128 + sb);                                  \
            gload_lds16(vpB + (size_t)r * (TSEQ * 2) + S0_ * 2 + bs,                \
                        (char*)Vs + r * 128 + sb);                                  \
        }                                                                           \
    }

    STAGE_KV(st0);
    for (int st = st0; st <= send; ++st) {
        const int S0 = st * 64;
        __syncthreads();

        __builtin_amdgcn_s_setprio(1);
        f32x4 sa[4];
#pragma unroll
        for (int sub = 0; sub < 4; ++sub) {
            const char* kr = (const char*)Ks + (16 * sub + c) * 128;
            short8 k0 = *(const short8*)(kr + ((g * 16) ^ bxor));
            short8 k1 = *(const short8*)(kr + ((64 + g * 16) ^ bxor));
            f32x4 t0 = f32x4{0.f, 0.f, 0.f, 0.f};
            t0 = __builtin_amdgcn_mfma_f32_16x16x32_bf16(k0, bq0, t0, 0, 0, 0);
            t0 = __builtin_amdgcn_mfma_f32_16x16x32_bf16(k1, bq1, t0, 0, 0, 0);
            sa[sub] = t0;
        }
        __builtin_amdgcn_s_setprio(0);

        float pvv[16];
#pragma unroll
        for (int sub = 0; sub < 4; ++sub)
#pragma unroll
            for (int i = 0; i < 4; ++i) pvv[4 * sub + i] = sa[sub][i];
        if (st == qb) {
#pragma unroll
            for (int sub = 0; sub < 4; ++sub)
#pragma unroll
                for (int i = 0; i < 4; ++i)
                    if (S0 + 16 * sub + 4 * g + i > q0 + c) pvv[4 * sub + i] = -INFINITY;
        }
        float tmax = pvv[0];
#pragma unroll
        for (int j = 1; j < 16; ++j) tmax = fmaxf(tmax, pvv[j]);
        tmax = fmaxf(tmax, __shfl_xor(tmax, 16));
        tmax = fmaxf(tmax, __shfl_xor(tmax, 32));
        if (!__all(tmax - m_ <= 8.0f)) {
            float mn = fmaxf(m_, tmax);
            float fac = __expf(m_ - mn);
            m_ = mn;
            l_ *= fac;
#pragma unroll
            for (int i = 0; i < 4; ++i) {
                float fr = __shfl(fac, 4 * g + i);
#pragma unroll
                for (int nf = 0; nf < 4; ++nf) o[nf][i] *= fr;
            }
        }
        float pp[16], rs = 0.f;
#pragma unroll
        for (int j = 0; j < 16; ++j) { pp[j] = __expf(pvv[j] - m_); rs += pp[j]; }
        rs += __shfl_xor(rs, 16);
        rs += __shfl_xor(rs, 32);
        l_ += rs;

#pragma unroll
        for (int sub = 0; sub < 4; ++sub) {
            unsigned lo = (__float_as_uint(pp[4 * sub + 0]) >> 16) |
                          (__float_as_uint(pp[4 * sub + 1]) & 0xffff0000u);
            unsigned hi = (__float_as_uint(pp[4 * sub + 2]) >> 16) |
                          (__float_as_uint(pp[4 * sub + 3]) & 0xffff0000u);
            *(uint2*)(pw + 16 * sub + 4 * g) = make_uint2(lo, hi);
        }
        asm volatile("s_waitcnt lgkmcnt(0)" ::: "memory");
        short8 pa0 = *(const short8*)(&Plds[w][c * 72 + g * 8]);
        short8 pa1 = *(const short8*)(&Plds[w][c * 72 + 32 + g * 8]);

        __builtin_amdgcn_s_setprio(1);
#pragma unroll
        for (int nf = 0; nf < 4; ++nf) {
            const char* vr = (const char*)Vs + (nf * 16 + c) * 128;
            short8 v0 = *(const short8*)(vr + ((g * 16) ^ bxor));
            short8 v1 = *(const short8*)(vr + ((64 + g * 16) ^ bxor));
            o[nf] = __builtin_amdgcn_mfma_f32_16x16x32_bf16(pa0, v0, o[nf], 0, 0, 0);
            o[nf] = __builtin_amdgcn_mfma_f32_16x16x32_bf16(pa1, v1, o[nf], 0, 0, 0);
        }
        __builtin_amdgcn_s_setprio(0);

        __syncthreads();
        if (st < send) STAGE_KV(st + 1);
    }
#undef STAGE_KV

    if (qb < 8) {
#pragma unroll
        for (int i = 0; i < 4; ++i) {
            float rl = 1.0f / __shfl(l_, 4 * g + i);
            int tt = q0 + 4 * g + i;
#pragma unroll
            for (int nf = 0; nf < 4; ++nf)
                attout[((size_t)(bb * TSEQ + tt)) * CC + hh * DH + nf * 16 + c] =
                    f2bf(o[nf][i] * rl);
        }
    } else {
        const size_t slot = (size_t)(bh * 32 + qb) * 4 + sc;
        float* op = opart + slot * 4096;
#pragma unroll
        for (int nf = 0; nf < 4; ++nf)
#pragma unroll
            for (int i = 0; i < 4; ++i)
                op[(size_t)(w * 16 + 4 * g + i) * 64 + nf * 16 + c] = o[nf][i];
        if (g == 0) {
            mlpart[slot * 128 + w * 16 + c] = m_;
            mlpart[slot * 128 + 64 + w * 16 + c] = l_;
        }
    }
}

// ---------------------------------------------------------------------------
// Combine partials for qb >= 8.  grid (B*H, 24) -> qb = blockIdx.y + 8.
// ---------------------------------------------------------------------------
__global__ __launch_bounds__(256) void flash_combine(
    const float* __restrict__ opart, const float* __restrict__ mlpart,
    ushort_t* __restrict__ attout)
{
    const int bh = blockIdx.x, qb = blockIdx.y + 8;
    const int bb = bh >> 4, hh = bh & 15;
    const int nsc = (qb >> 3) + 1;
    const int t = threadIdx.x, r = t >> 2, qc = t & 3;
    const size_t slot0 = (size_t)(bh * 32 + qb) * 4;

    float mi[4], li[4];
    float M = -INFINITY;
#pragma unroll
    for (int i = 0; i < 4; ++i) {
        if (i < nsc) {
            mi[i] = mlpart[(slot0 + i) * 128 + r];
            li[i] = mlpart[(slot0 + i) * 128 + 64 + r];
            M = fmaxf(M, mi[i]);
        }
    }
    float L = 0.f;
    f32x4 acc[4];
#pragma unroll
    for (int j = 0; j < 4; ++j) acc[j] = f32x4{0.f, 0.f, 0.f, 0.f};
#pragma unroll
    for (int i = 0; i < 4; ++i) {
        if (i < nsc) {
            float F = __expf(mi[i] - M);
            L += li[i] * F;
            const f32x4* orow = (const f32x4*)(opart + (slot0 + i) * 4096 +
                                               (size_t)r * 64 + qc * 16);
#pragma unroll
            for (int j = 0; j < 4; ++j) acc[j] += orow[j] * F;
        }
    }
    float rl = 1.0f / L;
    unsigned wb[8];
#pragma unroll
    for (int j = 0; j < 4; ++j) {
        wb[2 * j] = (unsigned)f2bf(acc[j][0] * rl) | ((unsigned)f2bf(acc[j][1] * rl) << 16);
        wb[2 * j + 1] = (unsigned)f2bf(acc[j][2] * rl) | ((unsigned)f2bf(acc[j][3] * rl) << 16);
    }
    ushort_t* dst = attout + ((size_t)(bb * TSEQ + qb * 64 + r)) * CC + hh * DH + qc * 16;
    ((uint4*)dst)[0] = make_uint4(wb[0], wb[1], wb[2], wb[3]);
    ((uint4*)dst)[1] = make_uint4(wb[4], wb[5], wb[6], wb[7]);
}

// ---------------------------------------------------------------------------
extern "C" void kernel_launch(void* const* d_in, const int* in_sizes, int n_in,
                              void* d_out, int out_size, void* d_ws, size_t ws_size,
                              hipStream_t stream)
{
    (void)in_sizes; (void)n_in; (void)out_size; (void)ws_size;
    const float* x     = (const float*)d_in[0];
    const float* ln1_g = (const float*)d_in[1];
    const float* ln1_b = (const float*)d_in[2];
    const float* Wq    = (const float*)d_in[3];
    const float* Wk    = (const float*)d_in[4];
    const float* Wv    = (const float*)d_in[5];
    const float* Wo    = (const float*)d_in[6];
    const float* bo    = (const float*)d_in[7];
    const float* ln2_g = (const float*)d_in[8];
    const float* ln2_b = (const float*)d_in[9];
    const float* W1    = (const float*)d_in[10];
    const float* b1    = (const float*)d_in[11];
    const float* W2    = (const float*)d_in[12];
    const float* b2    = (const float*)d_in[13];

    char* p = (char*)d_ws;
    ushort_t* hbuf  = (ushort_t*)p;  p += (size_t)BT * CC * 2;
    ushort_t* WqkvT = (ushort_t*)p;  p += (size_t)3 * CC * CC * 2;
    ushort_t* WoT   = (ushort_t*)p;  p += (size_t)CC * CC * 2;
    ushort_t* W1T   = (ushort_t*)p;  p += (size_t)CC * HID * 2;
    ushort_t* W2T   = (ushort_t*)p;  p += (size_t)HID * CC * 2;
    ushort_t* Qb    = (ushort_t*)p;  p += (size_t)BT * CC * 2;
    ushort_t* Kbuf  = (ushort_t*)p;  p += (size_t)BT * CC * 2;
    ushort_t* Vt    = (ushort_t*)p;  p += (size_t)BT * CC * 2;
    ushort_t* atto  = (ushort_t*)p;  p += (size_t)BT * CC * 2;
    float*    x1    = (float*)p;     p += (size_t)BT * CC * 4;
    ushort_t* h2    = (ushort_t*)p;  p += (size_t)BT * CC * 2;
    ushort_t* mid   = (ushort_t*)p;  p += (size_t)BT * HID * 2;
    float*    opart = (float*)p;     p += (size_t)4096 * 4096 * 4;   // flash partials / FFN2 bf16 partials
    float*    mlprt = (float*)p;     p += (size_t)4096 * 128 * 4;

    dim3 blk(256);
    transpose_qkv<<<dim3(DH / 32, CC / 32, 3 * NH), blk, 0, stream>>>(Wq, Wk, Wv, WqkvT);
    transpose_cvt<<<dim3(CC / 32, CC / 32, 1), blk, 0, stream>>>(Wo, WoT, CC, CC);
    transpose_cvt<<<dim3(HID / 32, CC / 32, 1), blk, 0, stream>>>(W1, W1T, CC, HID);
    transpose_cvt<<<dim3(CC / 32, HID / 32, 1), blk, 0, stream>>>(W2, W2T, HID, CC);

    ln_kernel<<<dim3(BT), blk, 0, stream>>>(x, ln1_g, ln1_b, hbuf);
    // QKV: [4096]x[3072]x[1024], 128^2 D=2
    gemm_tile<128, 128, 2, 2, 4, 4, 2, 2><<<dim3(BT / 128, 3072 / 128), blk, 0, stream>>>(
        hbuf, WqkvT, 3072, CC, CC, CC, nullptr, nullptr, Qb, Kbuf, Vt);
    flash_split<<<dim3(2 * NH, TSEQ / 64, 4), blk, 0, stream>>>(
        Qb, Kbuf, Vt, opart, mlprt, atto);
    flash_combine<<<dim3(2 * NH, TSEQ / 64 - 8), blk, 0, stream>>>(opart, mlprt, atto);
    // out projection + residual -> x1 (f32), 128x64 D=3
    gemm_tile<128, 64, 4, 1, 2, 4, 0, 3><<<dim3(BT / 128, CC / 64), blk, 0, stream>>>(
        atto, WoT, CC, CC, CC, CC, bo, x, (void*)x1, nullptr, nullptr);
    ln_kernel<<<dim3(BT), blk, 0, stream>>>(x1, ln2_g, ln2_b, h2);
    // FFN1: relu(h2 @ W1 + b1) -> mid, 128^2 D=2
    gemm_tile<128, 128, 2, 2, 4, 4, 1, 2><<<dim3(BT / 128, HID / 128), blk, 0, stream>>>(
        h2, W1T, HID, CC, CC, CC, b1, nullptr, (void*)mid, nullptr, nullptr);
    // FFN2 split-K: 4 chunks of K=1024 -> bf16 partials, 128x64 D=2, grid 32x16x4
    gemm_tile<128, 64, 4, 1, 2, 4, 3, 2><<<dim3(BT / 128, CC / 64, 4), blk, 0, stream>>>(
        mid, W2T, CC, HID / 4, HID, HID, nullptr, nullptr, (void*)opart, nullptr, nullptr);
    ffn2_combine<<<dim3(BT * CC / 8 / 256), blk, 0, stream>>>(
        (const ushort_t*)opart, b2, x1, (float*)d_out);
}

// Round 17
// 259.224 us; speedup vs baseline: 1.1167x; 1.0117x over previous
//
#include <hip/hip_runtime.h>

typedef unsigned short ushort_t;
typedef __attribute__((ext_vector_type(8))) short short8;
typedef __attribute__((ext_vector_type(4))) float f32x4;

#define BT 4096
#define TSEQ 2048
#define CC 1024
#define NH 16
#define DH 64
#define HID 4096
#define ATT_SCALE 0.03125f   /* C^-0.5 = 1/32 (reference scales by C, not DH) */

__device__ __forceinline__ ushort_t f2bf(float f) {
    unsigned u = __float_as_uint(f);
    u = u + 0x7fffu + ((u >> 16) & 1u);
    return (ushort_t)(u >> 16);
}
__device__ __forceinline__ float bf2f(ushort_t u) {
    return __uint_as_float(((unsigned)u) << 16);
}

typedef const __attribute__((address_space(1))) unsigned int* gptr_t;
typedef __attribute__((address_space(3))) unsigned int* lptr_t;
__device__ __forceinline__ void gload_lds16(const void* g, void* l) {
    __builtin_amdgcn_global_load_lds((gptr_t)g, (lptr_t)l, 16, 0, 0);
}

template <int N> __device__ __forceinline__ void vmcnt_wait() {
    if constexpr (N == 0)      asm volatile("s_waitcnt vmcnt(0)" ::: "memory");
    else if constexpr (N == 3) asm volatile("s_waitcnt vmcnt(3)" ::: "memory");
    else if constexpr (N == 4) asm volatile("s_waitcnt vmcnt(4)" ::: "memory");
    else if constexpr (N == 6) asm volatile("s_waitcnt vmcnt(6)" ::: "memory");
    else static_assert(N == 0, "unsupported vmcnt");
}

// ---------------------------------------------------------------------------
// Tiled transpose + f32->bf16 convert:  in [R][Cn] f32  ->  out [Cn][R] bf16
// ---------------------------------------------------------------------------
__global__ __launch_bounds__(256) void transpose_cvt(
    const float* __restrict__ in, ushort_t* __restrict__ out, int R, int Cn)
{
    __shared__ float tile[32][33];
    size_t off = (size_t)blockIdx.z * R * Cn;
    int c0 = blockIdx.x * 32, r0 = blockIdx.y * 32;
    int tx = threadIdx.x & 31, ty = threadIdx.x >> 5;
#pragma unroll
    for (int q = 0; q < 4; ++q)
        tile[ty + 8 * q][tx] = in[off + (size_t)(r0 + ty + 8 * q) * Cn + c0 + tx];
    __syncthreads();
#pragma unroll
    for (int q = 0; q < 4; ++q)
        out[off + (size_t)(c0 + ty + 8 * q) * R + r0 + tx] = f2bf(tile[tx][ty + 8 * q]);
}

// QKV weight transpose, merged: z = mat*16 + head; [C][64] -> [64][C] per head
__global__ __launch_bounds__(256) void transpose_qkv(
    const float* __restrict__ Wq, const float* __restrict__ Wk,
    const float* __restrict__ Wv, ushort_t* __restrict__ WqkvT)
{
    __shared__ float tile[32][33];
    int z = blockIdx.z, mat = z >> 4, head = z & 15;
    const float* in = (mat == 0 ? Wq : (mat == 1 ? Wk : Wv)) + (size_t)head * CC * DH;
    ushort_t* out = WqkvT + (size_t)z * DH * CC;
    int c0 = blockIdx.x * 32, r0 = blockIdx.y * 32;
    int tx = threadIdx.x & 31, ty = threadIdx.x >> 5;
#pragma unroll
    for (int q = 0; q < 4; ++q)
        tile[ty + 8 * q][tx] = in[(size_t)(r0 + ty + 8 * q) * DH + c0 + tx];
    __syncthreads();
#pragma unroll
    for (int q = 0; q < 4; ++q)
        out[(size_t)(c0 + ty + 8 * q) * CC + r0 + tx] = f2bf(tile[tx][ty + 8 * q]);
}

// ---------------------------------------------------------------------------
// LayerNorm row kernel: x f32 [rows][1024] -> out bf16.
// ---------------------------------------------------------------------------
__global__ __launch_bounds__(256) void ln_kernel(
    const float* __restrict__ x, const float* __restrict__ g,
    const float* __restrict__ b, ushort_t* __restrict__ out)
{
    int row = blockIdx.x;
    const float4 xv = ((const float4*)(x + (size_t)row * CC))[threadIdx.x];
    float s = xv.x + xv.y + xv.z + xv.w;
    float s2 = xv.x * xv.x + xv.y * xv.y + xv.z * xv.z + xv.w * xv.w;
#pragma unroll
    for (int d = 1; d < 64; d <<= 1) {
        s += __shfl_xor(s, d);
        s2 += __shfl_xor(s2, d);
    }
    __shared__ float ps[4], ps2[4];
    int w = threadIdx.x >> 6, lane = threadIdx.x & 63;
    if (lane == 0) { ps[w] = s; ps2[w] = s2; }
    __syncthreads();
    s = ps[0] + ps[1] + ps[2] + ps[3];
    s2 = ps2[0] + ps2[1] + ps2[2] + ps2[3];
    float mu = s * (1.0f / CC);
    float var = s2 * (1.0f / CC) - mu * mu;
    float rs = rsqrtf(var + 1e-5f);
    int c = threadIdx.x * 4;
    const float4 gv = ((const float4*)g)[threadIdx.x];
    const float4 bv = ((const float4*)b)[threadIdx.x];
    ushort_t u0 = f2bf((xv.x - mu) * rs * gv.x + bv.x);
    ushort_t u1 = f2bf((xv.y - mu) * rs * gv.y + bv.y);
    ushort_t u2 = f2bf((xv.z - mu) * rs * gv.z + bv.z);
    ushort_t u3 = f2bf((xv.w - mu) * rs * gv.w + bv.w);
    unsigned lo = (unsigned)u0 | ((unsigned)u1 << 16);
    unsigned hi = (unsigned)u2 | ((unsigned)u3 << 16);
    ((uint2*)(out + (size_t)row * CC + c))[0] = make_uint2(lo, hi);
}

// ---------------------------------------------------------------------------
// LDS-staged NT GEMM, depth-D ring buffer with COUNTED vmcnt.
// MODE 0: f32 out = acc + bias[n] + resid[m][n]
// MODE 1: bf16 out = relu(acc + bias[n])
// MODE 2: QKV scatter (Q prescaled by ATT_SCALE)
// MODE 3: split-K bf16 partial at plane blockIdx.z (A/B column offset z*K)
// ---------------------------------------------------------------------------
template <int BM, int BN, int WM, int WN, int MR, int NR, int MODE, int D>
__global__ __launch_bounds__(256) void gemm_tile(
    const ushort_t* __restrict__ A, const ushort_t* __restrict__ Bt,
    int N, int K, int lda, int ldb,
    const float* __restrict__ bias, const float* __restrict__ resid,
    void* __restrict__ out0, void* __restrict__ out1, void* __restrict__ out2)
{
    static_assert(WM * WN == 4 && WM * MR * 16 == BM && WN * NR * 16 == BN, "geom");
    constexpr int L = BM / 64 + BN / 64;
    __shared__ ushort_t As[D][BM * 32];
    __shared__ ushort_t Bs[D][BN * 32];

    const int t = threadIdx.x;
    const int w = t >> 6, lane = t & 63, g = lane >> 4, c = lane & 15;
    const int wr = w / WN, wc = w % WN;
    const int m0 = blockIdx.x * BM;
    const int n0 = blockIdx.y * BN;
    if (MODE == 3) {   // K-chunk column offset
        A += (size_t)blockIdx.z * K;
        Bt += (size_t)blockIdx.z * K;
    }

    f32x4 acc[MR][NR];
#pragma unroll
    for (int mi = 0; mi < MR; ++mi)
#pragma unroll
        for (int ni = 0; ni < NR; ++ni) acc[mi][ni] = f32x4{0.f, 0.f, 0.f, 0.f};

    const int arow = t >> 2, acol = (t & 3) * 8;
    const int aoff = (wr * MR * 16 + c) * 32 + g * 8;
    const int boff = (wc * NR * 16 + c) * 32 + g * 8;

#define STAGE(BUF, K0)                                                          \
    {                                                                           \
        _Pragma("unroll") for (int j = 0; j < BM / 64; ++j)                     \
            gload_lds16(A + (size_t)(m0 + j * 64 + arow) * lda + (K0) + acol,   \
                        As[BUF] + (size_t)j * 2048 + t * 8);                    \
        _Pragma("unroll") for (int j = 0; j < BN / 64; ++j)                     \
            gload_lds16(Bt + (size_t)(n0 + j * 64 + arow) * ldb + (K0) + acol,  \
                        Bs[BUF] + (size_t)j * 2048 + t * 8);                    \
    }

    const int nt = K >> 5;
#pragma unroll
    for (int d = 0; d < D - 1; ++d) STAGE(d, d * 32);

    int cur = 0;
    for (int ti = 0; ti < nt; ++ti) {
        const int ahead = nt - 1 - ti;
        if (ahead >= D - 1) {
            const int stg = (cur == 0) ? D - 1 : cur - 1;
            STAGE(stg, (ti + D - 1) * 32);
            vmcnt_wait<(D - 1) * L>();
        } else if (D == 3 && ahead == 1) {
            vmcnt_wait<L>();
        } else {
            vmcnt_wait<0>();
        }
        __builtin_amdgcn_sched_barrier(0);
        __builtin_amdgcn_s_barrier();

        const ushort_t* Ard = As[cur] + aoff;
        const ushort_t* Brd = Bs[cur] + boff;
        short8 af[MR], bf[NR];
#pragma unroll
        for (int mi = 0; mi < MR; ++mi) af[mi] = *(const short8*)(Ard + mi * 512);
#pragma unroll
        for (int ni = 0; ni < NR; ++ni) bf[ni] = *(const short8*)(Brd + ni * 512);
        __builtin_amdgcn_s_setprio(1);
#pragma unroll
        for (int mi = 0; mi < MR; ++mi)
#pragma unroll
            for (int ni = 0; ni < NR; ++ni)
                acc[mi][ni] = __builtin_amdgcn_mfma_f32_16x16x32_bf16(
                    af[mi], bf[ni], acc[mi][ni], 0, 0, 0);
        __builtin_amdgcn_s_setprio(0);

        __builtin_amdgcn_sched_barrier(0);
        __builtin_amdgcn_s_barrier();
        cur = (cur + 1 == D) ? 0 : cur + 1;
    }
#undef STAGE

#pragma unroll
    for (int mi = 0; mi < MR; ++mi)
#pragma unroll
        for (int ni = 0; ni < NR; ++ni)
#pragma unroll
            for (int i = 0; i < 4; ++i) {
                int row = m0 + wr * MR * 16 + mi * 16 + g * 4 + i;
                int col = n0 + wc * NR * 16 + ni * 16 + c;
                float v = acc[mi][ni][i];
                if (MODE == 0) {
                    v += bias[col] + resid[(size_t)row * N + col];
                    ((float*)out0)[(size_t)row * N + col] = v;
                } else if (MODE == 1) {
                    v += bias[col];
                    v = v > 0.f ? v : 0.f;
                    ((ushort_t*)out0)[(size_t)row * N + col] = f2bf(v);
                } else if (MODE == 3) {
                    ((ushort_t*)out0)[(size_t)blockIdx.z * BT * N + (size_t)row * N + col] =
                        f2bf(v);
                } else {
                    int bb = row >> 11, tt = row & (TSEQ - 1);
                    if (col < 1024) {
                        int head = col >> 6, d = col & 63;
                        ((ushort_t*)out0)[((size_t)(bb * NH + head) * TSEQ + tt) * DH + d] =
                            f2bf(v * ATT_SCALE);
                    } else if (col < 2048) {
                        int head = (col - 1024) >> 6, d = col & 63;
                        ((ushort_t*)out1)[((size_t)(bb * NH + head) * TSEQ + tt) * DH + d] = f2bf(v);
                    } else {
                        int head = (col - 2048) >> 6, d = col & 63;
                        ((ushort_t*)out2)[((size_t)(bb * NH + head) * DH + d) * TSEQ + tt] = f2bf(v);
                    }
                }
            }
}

// ---------------------------------------------------------------------------
// FFN2 combine: out[m][n] = sum_{z<4} bf16 parts[z][m][n] + bias[n] + resid
// ---------------------------------------------------------------------------
__global__ __launch_bounds__(256) void ffn2_combine(
    const ushort_t* __restrict__ parts, const float* __restrict__ bias,
    const float* __restrict__ resid, float* __restrict__ out)
{
    const size_t off = ((size_t)blockIdx.x * 256 + threadIdx.x) * 8;
    const int col = (int)(off & 1023);
    short8 p0 = *(const short8*)(parts + off);
    short8 p1 = *(const short8*)(parts + (size_t)BT * CC + off);
    short8 p2 = *(const short8*)(parts + (size_t)2 * BT * CC + off);
    short8 p3 = *(const short8*)(parts + (size_t)3 * BT * CC + off);
    float4 r0 = ((const float4*)(resid + off))[0];
    float4 r1 = ((const float4*)(resid + off + 4))[0];
    float4 b0 = ((const float4*)(bias + col))[0];
    float4 b1 = ((const float4*)(bias + col + 4))[0];
    float o[8];
#pragma unroll
    for (int j = 0; j < 8; ++j)
        o[j] = bf2f((ushort_t)p0[j]) + bf2f((ushort_t)p1[j]) +
               bf2f((ushort_t)p2[j]) + bf2f((ushort_t)p3[j]);
    float4 w0 = make_float4(o[0] + b0.x + r0.x, o[1] + b0.y + r0.y,
                            o[2] + b0.z + r0.z, o[3] + b0.w + r0.w);
    float4 w1 = make_float4(o[4] + b1.x + r1.x, o[5] + b1.y + r1.y,
                            o[6] + b1.z + r1.z, o[7] + b1.w + r1.w);
    ((float4*)(out + off))[0] = w0;
    ((float4*)(out + off + 4))[0] = w1;
}

// ---------------------------------------------------------------------------
// Split flash: K/V tiles staged per block into LDS (global_load_lds,
// inverse-swizzled source), shared by 4 waves.  grid (B*H, T/64, 4 chunks).
// ---------------------------------------------------------------------------
__global__ __launch_bounds__(256) void flash_split(
    const ushort_t* __restrict__ Q, const ushort_t* __restrict__ Kb,
    const ushort_t* __restrict__ Vt, float* __restrict__ opart,
    float* __restrict__ mlpart, ushort_t* __restrict__ attout)
{
    __shared__ ushort_t Ks[64 * 64];
    __shared__ ushort_t Vs[64 * 64];
    __shared__ ushort_t Plds[4][16 * 72];
    const int t = threadIdx.x;
    const int w = t >> 6, lane = t & 63;
    const int g = lane >> 4, c = lane & 15;
    const int bh = blockIdx.x, qb = blockIdx.y, sc = blockIdx.z;
    if (sc * 8 > qb) return;
    const int bb = bh >> 4, hh = bh & 15;
    const int q0 = qb * 64 + w * 16;
    const ushort_t* qp = Q + (size_t)bh * TSEQ * DH;
    const char* kpB = (const char*)(Kb + (size_t)bh * TSEQ * DH);
    const char* vpB = (const char*)(Vt + (size_t)bh * DH * TSEQ);

    const short8 bq0 = *(const short8*)(qp + (size_t)(q0 + c) * DH + g * 8);
    const short8 bq1 = *(const short8*)(qp + (size_t)(q0 + c) * DH + 32 + g * 8);

    float m_ = -INFINITY, l_ = 0.f;
    f32x4 o[4];
#pragma unroll
    for (int nf = 0; nf < 4; ++nf) o[nf] = f32x4{0.f, 0.f, 0.f, 0.f};

    const int st0 = sc * 8;
    const int send = (st0 + 7 < qb) ? st0 + 7 : qb;
    ushort_t* pw = &Plds[w][c * 72];
    const unsigned bxor = (unsigned)((c & 7) << 4);

    const int srow = t >> 3, sb = (t & 7) * 16;
#define STAGE_KV(ST)                                                                \
    {                                                                               \
        const int S0_ = (ST) * 64;                                                  \
        _Pragma("unroll") for (int j = 0; j < 2; ++j) {                             \
            int r = j * 32 + srow;                                                  \
            int bs = sb ^ ((r & 7) << 4);                                           \
            gload_lds16(kpB + (size_t)(S0_ + r) * 128 + bs,                         \
                        (char*)Ks + r * 128 + sb);                                  \
            gload_lds16(vpB + (size_t)r * (TSEQ * 2) + S0_ * 2 + bs,                \
                        (char*)Vs + r * 128 + sb);                                  \
        }                                                                           \
    }

    STAGE_KV(st0);
    for (int st = st0; st <= send; ++st) {
        const int S0 = st * 64;
        __syncthreads();

        __builtin_amdgcn_s_setprio(1);
        f32x4 sa[4];
#pragma unroll
        for (int sub = 0; sub < 4; ++sub) {
            const char* kr = (const char*)Ks + (16 * sub + c) * 128;
            short8 k0 = *(const short8*)(kr + ((g * 16) ^ bxor));
            short8 k1 = *(const short8*)(kr + ((64 + g * 16) ^ bxor));
            f32x4 t0 = f32x4{0.f, 0.f, 0.f, 0.f};
            t0 = __builtin_amdgcn_mfma_f32_16x16x32_bf16(k0, bq0, t0, 0, 0, 0);
            t0 = __builtin_amdgcn_mfma_f32_16x16x32_bf16(k1, bq1, t0, 0, 0, 0);
            sa[sub] = t0;
        }
        __builtin_amdgcn_s_setprio(0);

        float pvv[16];
#pragma unroll
        for (int sub = 0; sub < 4; ++sub)
#pragma unroll
            for (int i = 0; i < 4; ++i) pvv[4 * sub + i] = sa[sub][i];
        if (st == qb) {
#pragma unroll
            for (int sub = 0; sub < 4; ++sub)
#pragma unroll
                for (int i = 0; i < 4; ++i)
                    if (S0 + 16 * sub + 4 * g + i > q0 + c) pvv[4 * sub + i] = -INFINITY;
        }
        float tmax = pvv[0];
#pragma unroll
        for (int j = 1; j < 16; ++j) tmax = fmaxf(tmax, pvv[j]);
        tmax = fmaxf(tmax, __shfl_xor(tmax, 16));
        tmax = fmaxf(tmax, __shfl_xor(tmax, 32));
        if (!__all(tmax - m_ <= 8.0f)) {
            float mn = fmaxf(m_, tmax);
            float fac = __expf(m_ - mn);
            m_ = mn;
            l_ *= fac;
#pragma unroll
            for (int i = 0; i < 4; ++i) {
                float fr = __shfl(fac, 4 * g + i);
#pragma unroll
                for (int nf = 0; nf < 4; ++nf) o[nf][i] *= fr;
            }
        }
        float pp[16], rs = 0.f;
#pragma unroll
        for (int j = 0; j < 16; ++j) { pp[j] = __expf(pvv[j] - m_); rs += pp[j]; }
        rs += __shfl_xor(rs, 16);
        rs += __shfl_xor(rs, 32);
        l_ += rs;

#pragma unroll
        for (int sub = 0; sub < 4; ++sub) {
            unsigned lo = (__float_as_uint(pp[4 * sub + 0]) >> 16) |
                          (__float_as_uint(pp[4 * sub + 1]) & 0xffff0000u);
            unsigned hi = (__float_as_uint(pp[4 * sub + 2]) >> 16) |
                          (__float_as_uint(pp[4 * sub + 3]) & 0xffff0000u);
            *(uint2*)(pw + 16 * sub + 4 * g) = make_uint2(lo, hi);
        }
        asm volatile("s_waitcnt lgkmcnt(0)" ::: "memory");
        short8 pa0 = *(const short8*)(&Plds[w][c * 72 + g * 8]);
        short8 pa1 = *(const short8*)(&Plds[w][c * 72 + 32 + g * 8]);

        __builtin_amdgcn_s_setprio(1);
#pragma unroll
        for (int nf = 0; nf < 4; ++nf) {
            const char* vr = (const char*)Vs + (nf * 16 + c) * 128;
            short8 v0 = *(const short8*)(vr + ((g * 16) ^ bxor));
            short8 v1 = *(const short8*)(vr + ((64 + g * 16) ^ bxor));
            o[nf] = __builtin_amdgcn_mfma_f32_16x16x32_bf16(pa0, v0, o[nf], 0, 0, 0);
            o[nf] = __builtin_amdgcn_mfma_f32_16x16x32_bf16(pa1, v1, o[nf], 0, 0, 0);
        }
        __builtin_amdgcn_s_setprio(0);

        __syncthreads();
        if (st < send) STAGE_KV(st + 1);
    }
#undef STAGE_KV

    if (qb < 8) {
#pragma unroll
        for (int i = 0; i < 4; ++i) {
            float rl = 1.0f / __shfl(l_, 4 * g + i);
            int tt = q0 + 4 * g + i;
#pragma unroll
            for (int nf = 0; nf < 4; ++nf)
                attout[((size_t)(bb * TSEQ + tt)) * CC + hh * DH + nf * 16 + c] =
                    f2bf(o[nf][i] * rl);
        }
    } else {
        const size_t slot = (size_t)(bh * 32 + qb) * 4 + sc;
        float* op = opart + slot * 4096;
#pragma unroll
        for (int nf = 0; nf < 4; ++nf)
#pragma unroll
            for (int i = 0; i < 4; ++i)
                op[(size_t)(w * 16 + 4 * g + i) * 64 + nf * 16 + c] = o[nf][i];
        if (g == 0) {
            mlpart[slot * 128 + w * 16 + c] = m_;
            mlpart[slot * 128 + 64 + w * 16 + c] = l_;
        }
    }
}

// ---------------------------------------------------------------------------
// Combine partials for qb >= 8.  grid (B*H, 24) -> qb = blockIdx.y + 8.
// ---------------------------------------------------------------------------
__global__ __launch_bounds__(256) void flash_combine(
    const float* __restrict__ opart, const float* __restrict__ mlpart,
    ushort_t* __restrict__ attout)
{
    const int bh = blockIdx.x, qb = blockIdx.y + 8;
    const int bb = bh >> 4, hh = bh & 15;
    const int nsc = (qb >> 3) + 1;
    const int t = threadIdx.x, r = t >> 2, qc = t & 3;
    const size_t slot0 = (size_t)(bh * 32 + qb) * 4;

    float mi[4], li[4];
    float M = -INFINITY;
#pragma unroll
    for (int i = 0; i < 4; ++i) {
        if (i < nsc) {
            mi[i] = mlpart[(slot0 + i) * 128 + r];
            li[i] = mlpart[(slot0 + i) * 128 + 64 + r];
            M = fmaxf(M, mi[i]);
        }
    }
    float L = 0.f;
    f32x4 acc[4];
#pragma unroll
    for (int j = 0; j < 4; ++j) acc[j] = f32x4{0.f, 0.f, 0.f, 0.f};
#pragma unroll
    for (int i = 0; i < 4; ++i) {
        if (i < nsc) {
            float F = __expf(mi[i] - M);
            L += li[i] * F;
            const f32x4* orow = (const f32x4*)(opart + (slot0 + i) * 4096 +
                                               (size_t)r * 64 + qc * 16);
#pragma unroll
            for (int j = 0; j < 4; ++j) acc[j] += orow[j] * F;
        }
    }
    float rl = 1.0f / L;
    unsigned wb[8];
#pragma unroll
    for (int j = 0; j < 4; ++j) {
        wb[2 * j] = (unsigned)f2bf(acc[j][0] * rl) | ((unsigned)f2bf(acc[j][1] * rl) << 16);
        wb[2 * j + 1] = (unsigned)f2bf(acc[j][2] * rl) | ((unsigned)f2bf(acc[j][3] * rl) << 16);
    }
    ushort_t* dst = attout + ((size_t)(bb * TSEQ + qb * 64 + r)) * CC + hh * DH + qc * 16;
    ((uint4*)dst)[0] = make_uint4(wb[0], wb[1], wb[2], wb[3]);
    ((uint4*)dst)[1] = make_uint4(wb[4], wb[5], wb[6], wb[7]);
}

// ---------------------------------------------------------------------------
extern "C" void kernel_launch(void* const* d_in, const int* in_sizes, int n_in,
                              void* d_out, int out_size, void* d_ws, size_t ws_size,
                              hipStream_t stream)
{
    (void)in_sizes; (void)n_in; (void)out_size; (void)ws_size;
    const float* x     = (const float*)d_in[0];
    const float* ln1_g = (const float*)d_in[1];
    const float* ln1_b = (const float*)d_in[2];
    const float* Wq    = (const float*)d_in[3];
    const float* Wk    = (const float*)d_in[4];
    const float* Wv    = (const float*)d_in[5];
    const float* Wo    = (const float*)d_in[6];
    const float* bo    = (const float*)d_in[7];
    const float* ln2_g = (const float*)d_in[8];
    const float* ln2_b = (const float*)d_in[9];
    const float* W1    = (const float*)d_in[10];
    const float* b1    = (const float*)d_in[11];
    const float* W2    = (const float*)d_in[12];
    const float* b2    = (const float*)d_in[13];

    char* p = (char*)d_ws;
    ushort_t* hbuf  = (ushort_t*)p;  p += (size_t)BT * CC * 2;
    ushort_t* WqkvT = (ushort_t*)p;  p += (size_t)3 * CC * CC * 2;
    ushort_t* WoT   = (ushort_t*)p;  p += (size_t)CC * CC * 2;
    ushort_t* W1T   = (ushort_t*)p;  p += (size_t)CC * HID * 2;
    ushort_t* W2T   = (ushort_t*)p;  p += (size_t)HID * CC * 2;
    ushort_t* Qb    = (ushort_t*)p;  p += (size_t)BT * CC * 2;
    ushort_t* Kbuf  = (ushort_t*)p;  p += (size_t)BT * CC * 2;
    ushort_t* Vt    = (ushort_t*)p;  p += (size_t)BT * CC * 2;
    ushort_t* atto  = (ushort_t*)p;  p += (size_t)BT * CC * 2;
    float*    x1    = (float*)p;     p += (size_t)BT * CC * 4;
    ushort_t* h2    = (ushort_t*)p;  p += (size_t)BT * CC * 2;
    ushort_t* mid   = (ushort_t*)p;  p += (size_t)BT * HID * 2;
    float*    opart = (float*)p;     p += (size_t)4096 * 4096 * 4;   // flash partials / FFN2 bf16 partials
    float*    mlprt = (float*)p;     p += (size_t)4096 * 128 * 4;

    dim3 blk(256);
    transpose_qkv<<<dim3(DH / 32, CC / 32, 3 * NH), blk, 0, stream>>>(Wq, Wk, Wv, WqkvT);
    transpose_cvt<<<dim3(CC / 32, CC / 32, 1), blk, 0, stream>>>(Wo, WoT, CC, CC);
    transpose_cvt<<<dim3(HID / 32, CC / 32, 1), blk, 0, stream>>>(W1, W1T, CC, HID);
    transpose_cvt<<<dim3(CC / 32, HID / 32, 1), blk, 0, stream>>>(W2, W2T, HID, CC);

    ln_kernel<<<dim3(BT), blk, 0, stream>>>(x, ln1_g, ln1_b, hbuf);
    // QKV: [4096]x[3072]x[1024], 128^2 D=2
    gemm_tile<128, 128, 2, 2, 4, 4, 2, 2><<<dim3(BT / 128, 3072 / 128), blk, 0, stream>>>(
        hbuf, WqkvT, 3072, CC, CC, CC, nullptr, nullptr, Qb, Kbuf, Vt);
    flash_split<<<dim3(2 * NH, TSEQ / 64, 4), blk, 0, stream>>>(
        Qb, Kbuf, Vt, opart, mlprt, atto);
    flash_combine<<<dim3(2 * NH, TSEQ / 64 - 8), blk, 0, stream>>>(opart, mlprt, atto);
    // out projection + residual -> x1 (f32), 128x64 D=3
    gemm_tile<128, 64, 4, 1, 2, 4, 0, 3><<<dim3(BT / 128, CC / 64), blk, 0, stream>>>(
        atto, WoT, CC, CC, CC, CC, bo, x, (void*)x1, nullptr, nullptr);
    ln_kernel<<<dim3(BT), blk, 0, stream>>>(x1, ln2_g, ln2_b, h2);
    // FFN1: relu(h2 @ W1 + b1) -> mid, 128^2 D=2
    gemm_tile<128, 128, 2, 2, 4, 4, 1, 2><<<dim3(BT / 128, HID / 128), blk, 0, stream>>>(
        h2, W1T, HID, CC, CC, CC, b1, nullptr, (void*)mid, nullptr, nullptr);
    // FFN2 split-K: 4 chunks of K=1024, 128^2 geometry (16 MFMA/wave/step),
    // grid 32x8x4 = 1024 blocks = 4 blocks/CU -> bf16 partials in opart
    gemm_tile<128, 128, 2, 2, 4, 4, 3, 2><<<dim3(BT / 128, CC / 128, 4), blk, 0, stream>>>(
        mid, W2T, CC, HID / 4, HID, HID, nullptr, nullptr, (void*)opart, nullptr, nullptr);
    ffn2_combine<<<dim3(BT * CC / 8 / 256), blk, 0, stream>>>(
        (const ushort_t*)opart, b2, x1, (float*)d_out);
}

// Round 20
// 256.580 us; speedup vs baseline: 1.1283x; 1.0103x over previous
//
#include <hip/hip_runtime.h>

typedef unsigned short ushort_t;
typedef __attribute__((ext_vector_type(8))) short short8;
typedef __attribute__((ext_vector_type(4))) float f32x4;

#define BT 4096
#define TSEQ 2048
#define CC 1024
#define NH 16
#define DH 64
#define HID 4096
#define ATT_SCALE 0.03125f   /* C^-0.5 = 1/32 (reference scales by C, not DH) */

__device__ __forceinline__ ushort_t f2bf(float f) {
    unsigned u = __float_as_uint(f);
    u = u + 0x7fffu + ((u >> 16) & 1u);
    return (ushort_t)(u >> 16);
}
__device__ __forceinline__ float bf2f(ushort_t u) {
    return __uint_as_float(((unsigned)u) << 16);
}

typedef const __attribute__((address_space(1))) unsigned int* gptr_t;
typedef __attribute__((address_space(3))) unsigned int* lptr_t;
__device__ __forceinline__ void gload_lds16(const void* g, void* l) {
    __builtin_amdgcn_global_load_lds((gptr_t)g, (lptr_t)l, 16, 0, 0);
}

template <int N> __device__ __forceinline__ void vmcnt_wait() {
    if constexpr (N == 0)      asm volatile("s_waitcnt vmcnt(0)" ::: "memory");
    else if constexpr (N == 3) asm volatile("s_waitcnt vmcnt(3)" ::: "memory");
    else if constexpr (N == 4) asm volatile("s_waitcnt vmcnt(4)" ::: "memory");
    else if constexpr (N == 6) asm volatile("s_waitcnt vmcnt(6)" ::: "memory");
    else static_assert(N == 0, "unsupported vmcnt");
}

// ---------------------------------------------------------------------------
// Tiled transpose + f32->bf16 convert:  in [R][Cn] f32  ->  out [Cn][R] bf16
// ---------------------------------------------------------------------------
__global__ __launch_bounds__(256) void transpose_cvt(
    const float* __restrict__ in, ushort_t* __restrict__ out, int R, int Cn)
{
    __shared__ float tile[32][33];
    size_t off = (size_t)blockIdx.z * R * Cn;
    int c0 = blockIdx.x * 32, r0 = blockIdx.y * 32;
    int tx = threadIdx.x & 31, ty = threadIdx.x >> 5;
#pragma unroll
    for (int q = 0; q < 4; ++q)
        tile[ty + 8 * q][tx] = in[off + (size_t)(r0 + ty + 8 * q) * Cn + c0 + tx];
    __syncthreads();
#pragma unroll
    for (int q = 0; q < 4; ++q)
        out[off + (size_t)(c0 + ty + 8 * q) * R + r0 + tx] = f2bf(tile[tx][ty + 8 * q]);
}

// QKV weight transpose, merged: z = mat*16 + head; [C][64] -> [64][C] per head
__global__ __launch_bounds__(256) void transpose_qkv(
    const float* __restrict__ Wq, const float* __restrict__ Wk,
    const float* __restrict__ Wv, ushort_t* __restrict__ WqkvT)
{
    __shared__ float tile[32][33];
    int z = blockIdx.z, mat = z >> 4, head = z & 15;
    const float* in = (mat == 0 ? Wq : (mat == 1 ? Wk : Wv)) + (size_t)head * CC * DH;
    ushort_t* out = WqkvT + (size_t)z * DH * CC;
    int c0 = blockIdx.x * 32, r0 = blockIdx.y * 32;
    int tx = threadIdx.x & 31, ty = threadIdx.x >> 5;
#pragma unroll
    for (int q = 0; q < 4; ++q)
        tile[ty + 8 * q][tx] = in[(size_t)(r0 + ty + 8 * q) * DH + c0 + tx];
    __syncthreads();
#pragma unroll
    for (int q = 0; q < 4; ++q)
        out[(size_t)(c0 + ty + 8 * q) * CC + r0 + tx] = f2bf(tile[tx][ty + 8 * q]);
}

// ---------------------------------------------------------------------------
// LayerNorm row kernel: x f32 [rows][1024] -> out bf16.
// ---------------------------------------------------------------------------
__global__ __launch_bounds__(256) void ln_kernel(
    const float* __restrict__ x, const float* __restrict__ g,
    const float* __restrict__ b, ushort_t* __restrict__ out)
{
    int row = blockIdx.x;
    const float4 xv = ((const float4*)(x + (size_t)row * CC))[threadIdx.x];
    float s = xv.x + xv.y + xv.z + xv.w;
    float s2 = xv.x * xv.x + xv.y * xv.y + xv.z * xv.z + xv.w * xv.w;
#pragma unroll
    for (int d = 1; d < 64; d <<= 1) {
        s += __shfl_xor(s, d);
        s2 += __shfl_xor(s2, d);
    }
    __shared__ float ps[4], ps2[4];
    int w = threadIdx.x >> 6, lane = threadIdx.x & 63;
    if (lane == 0) { ps[w] = s; ps2[w] = s2; }
    __syncthreads();
    s = ps[0] + ps[1] + ps[2] + ps[3];
    s2 = ps2[0] + ps2[1] + ps2[2] + ps2[3];
    float mu = s * (1.0f / CC);
    float var = s2 * (1.0f / CC) - mu * mu;
    float rs = rsqrtf(var + 1e-5f);
    int c = threadIdx.x * 4;
    const float4 gv = ((const float4*)g)[threadIdx.x];
    const float4 bv = ((const float4*)b)[threadIdx.x];
    ushort_t u0 = f2bf((xv.x - mu) * rs * gv.x + bv.x);
    ushort_t u1 = f2bf((xv.y - mu) * rs * gv.y + bv.y);
    ushort_t u2 = f2bf((xv.z - mu) * rs * gv.z + bv.z);
    ushort_t u3 = f2bf((xv.w - mu) * rs * gv.w + bv.w);
    unsigned lo = (unsigned)u0 | ((unsigned)u1 << 16);
    unsigned hi = (unsigned)u2 | ((unsigned)u3 << 16);
    ((uint2*)(out + (size_t)row * CC + c))[0] = make_uint2(lo, hi);
}

// ---------------------------------------------------------------------------
// LDS-staged NT GEMM, depth-D ring buffer with COUNTED vmcnt.
// MODE 0: f32 out = acc + bias[n] + resid[m][n]
// MODE 1: bf16 out = relu(acc + bias[n])
// MODE 2: QKV scatter (Q prescaled by ATT_SCALE)
// MODE 3: split-K bf16 partial at plane blockIdx.z (A/B column offset z*K)
// ---------------------------------------------------------------------------
template <int BM, int BN, int WM, int WN, int MR, int NR, int MODE, int D>
__global__ __launch_bounds__(256) void gemm_tile(
    const ushort_t* __restrict__ A, const ushort_t* __restrict__ Bt,
    int N, int K, int lda, int ldb,
    const float* __restrict__ bias, const float* __restrict__ resid,
    void* __restrict__ out0, void* __restrict__ out1, void* __restrict__ out2)
{
    static_assert(WM * WN == 4 && WM * MR * 16 == BM && WN * NR * 16 == BN, "geom");
    constexpr int L = BM / 64 + BN / 64;
    __shared__ ushort_t As[D][BM * 32];
    __shared__ ushort_t Bs[D][BN * 32];

    const int t = threadIdx.x;
    const int w = t >> 6, lane = t & 63, g = lane >> 4, c = lane & 15;
    const int wr = w / WN, wc = w % WN;
    const int m0 = blockIdx.x * BM;
    const int n0 = blockIdx.y * BN;
    if (MODE == 3) {   // K-chunk column offset
        A += (size_t)blockIdx.z * K;
        Bt += (size_t)blockIdx.z * K;
    }

    f32x4 acc[MR][NR];
#pragma unroll
    for (int mi = 0; mi < MR; ++mi)
#pragma unroll
        for (int ni = 0; ni < NR; ++ni) acc[mi][ni] = f32x4{0.f, 0.f, 0.f, 0.f};

    const int arow = t >> 2, acol = (t & 3) * 8;
    const int aoff = (wr * MR * 16 + c) * 32 + g * 8;
    const int boff = (wc * NR * 16 + c) * 32 + g * 8;

#define STAGE(BUF, K0)                                                          \
    {                                                                           \
        _Pragma("unroll") for (int j = 0; j < BM / 64; ++j)                     \
            gload_lds16(A + (size_t)(m0 + j * 64 + arow) * lda + (K0) + acol,   \
                        As[BUF] + (size_t)j * 2048 + t * 8);                    \
        _Pragma("unroll") for (int j = 0; j < BN / 64; ++j)                     \
            gload_lds16(Bt + (size_t)(n0 + j * 64 + arow) * ldb + (K0) + acol,  \
                        Bs[BUF] + (size_t)j * 2048 + t * 8);                    \
    }

    const int nt = K >> 5;
#pragma unroll
    for (int d = 0; d < D - 1; ++d) STAGE(d, d * 32);

    int cur = 0;
    for (int ti = 0; ti < nt; ++ti) {
        const int ahead = nt - 1 - ti;
        if (ahead >= D - 1) {
            const int stg = (cur == 0) ? D - 1 : cur - 1;
            STAGE(stg, (ti + D - 1) * 32);
            vmcnt_wait<(D - 1) * L>();
        } else if (D == 3 && ahead == 1) {
            vmcnt_wait<L>();
        } else {
            vmcnt_wait<0>();
        }
        __builtin_amdgcn_sched_barrier(0);
        __builtin_amdgcn_s_barrier();

        const ushort_t* Ard = As[cur] + aoff;
        const ushort_t* Brd = Bs[cur] + boff;
        short8 af[MR], bf[NR];
#pragma unroll
        for (int mi = 0; mi < MR; ++mi) af[mi] = *(const short8*)(Ard + mi * 512);
#pragma unroll
        for (int ni = 0; ni < NR; ++ni) bf[ni] = *(const short8*)(Brd + ni * 512);
        __builtin_amdgcn_s_setprio(1);
#pragma unroll
        for (int mi = 0; mi < MR; ++mi)
#pragma unroll
            for (int ni = 0; ni < NR; ++ni)
                acc[mi][ni] = __builtin_amdgcn_mfma_f32_16x16x32_bf16(
                    af[mi], bf[ni], acc[mi][ni], 0, 0, 0);
        __builtin_amdgcn_s_setprio(0);

        __builtin_amdgcn_sched_barrier(0);
        __builtin_amdgcn_s_barrier();
        cur = (cur + 1 == D) ? 0 : cur + 1;
    }
#undef STAGE

#pragma unroll
    for (int mi = 0; mi < MR; ++mi)
#pragma unroll
        for (int ni = 0; ni < NR; ++ni)
#pragma unroll
            for (int i = 0; i < 4; ++i) {
                int row = m0 + wr * MR * 16 + mi * 16 + g * 4 + i;
                int col = n0 + wc * NR * 16 + ni * 16 + c;
                float v = acc[mi][ni][i];
                if (MODE == 0) {
                    v += bias[col] + resid[(size_t)row * N + col];
                    ((float*)out0)[(size_t)row * N + col] = v;
                } else if (MODE == 1) {
                    v += bias[col];
                    v = v > 0.f ? v : 0.f;
                    ((ushort_t*)out0)[(size_t)row * N + col] = f2bf(v);
                } else if (MODE == 3) {
                    ((ushort_t*)out0)[(size_t)blockIdx.z * BT * N + (size_t)row * N + col] =
                        f2bf(v);
                } else {
                    int bb = row >> 11, tt = row & (TSEQ - 1);
                    if (col < 1024) {
                        int head = col >> 6, d = col & 63;
                        ((ushort_t*)out0)[((size_t)(bb * NH + head) * TSEQ + tt) * DH + d] =
                            f2bf(v * ATT_SCALE);
                    } else if (col < 2048) {
                        int head = (col - 1024) >> 6, d = col & 63;
                        ((ushort_t*)out1)[((size_t)(bb * NH + head) * TSEQ + tt) * DH + d] = f2bf(v);
                    } else {
                        int head = (col - 2048) >> 6, d = col & 63;
                        ((ushort_t*)out2)[((size_t)(bb * NH + head) * DH + d) * TSEQ + tt] = f2bf(v);
                    }
                }
            }
}

// ---------------------------------------------------------------------------
// FFN2 combine: out[m][n] = sum_{z<2} bf16 parts[z][m][n] + bias[n] + resid
// ---------------------------------------------------------------------------
__global__ __launch_bounds__(256) void ffn2_combine(
    const ushort_t* __restrict__ parts, const float* __restrict__ bias,
    const float* __restrict__ resid, float* __restrict__ out)
{
    const size_t off = ((size_t)blockIdx.x * 256 + threadIdx.x) * 8;
    const int col = (int)(off & 1023);
    short8 p0 = *(const short8*)(parts + off);
    short8 p1 = *(const short8*)(parts + (size_t)BT * CC + off);
    float4 r0 = ((const float4*)(resid + off))[0];
    float4 r1 = ((const float4*)(resid + off + 4))[0];
    float4 b0 = ((const float4*)(bias + col))[0];
    float4 b1 = ((const float4*)(bias + col + 4))[0];
    float o[8];
#pragma unroll
    for (int j = 0; j < 8; ++j)
        o[j] = bf2f((ushort_t)p0[j]) + bf2f((ushort_t)p1[j]);
    float4 w0 = make_float4(o[0] + b0.x + r0.x, o[1] + b0.y + r0.y,
                            o[2] + b0.z + r0.z, o[3] + b0.w + r0.w);
    float4 w1 = make_float4(o[4] + b1.x + r1.x, o[5] + b1.y + r1.y,
                            o[6] + b1.z + r1.z, o[7] + b1.w + r1.w);
    ((float4*)(out + off))[0] = w0;
    ((float4*)(out + off + 4))[0] = w1;
}

// ---------------------------------------------------------------------------
// Split flash: K/V tiles staged per block into LDS (global_load_lds,
// inverse-swizzled source), shared by 4 waves.  grid (B*H, T/64, 4 chunks).
// ---------------------------------------------------------------------------
__global__ __launch_bounds__(256) void flash_split(
    const ushort_t* __restrict__ Q, const ushort_t* __restrict__ Kb,
    const ushort_t* __restrict__ Vt, float* __restrict__ opart,
    float* __restrict__ mlpart, ushort_t* __restrict__ attout)
{
    __shared__ ushort_t Ks[64 * 64];
    __shared__ ushort_t Vs[64 * 64];
    __shared__ ushort_t Plds[4][16 * 72];
    const int t = threadIdx.x;
    const int w = t >> 6, lane = t & 63;
    const int g = lane >> 4, c = lane & 15;
    const int bh = blockIdx.x, qb = blockIdx.y, sc = blockIdx.z;
    if (sc * 8 > qb) return;
    const int bb = bh >> 4, hh = bh & 15;
    const int q0 = qb * 64 + w * 16;
    const ushort_t* qp = Q + (size_t)bh * TSEQ * DH;
    const char* kpB = (const char*)(Kb + (size_t)bh * TSEQ * DH);
    const char* vpB = (const char*)(Vt + (size_t)bh * DH * TSEQ);

    const short8 bq0 = *(const short8*)(qp + (size_t)(q0 + c) * DH + g * 8);
    const short8 bq1 = *(const short8*)(qp + (size_t)(q0 + c) * DH + 32 + g * 8);

    float m_ = -INFINITY, l_ = 0.f;
    f32x4 o[4];
#pragma unroll
    for (int nf = 0; nf < 4; ++nf) o[nf] = f32x4{0.f, 0.f, 0.f, 0.f};

    const int st0 = sc * 8;
    const int send = (st0 + 7 < qb) ? st0 + 7 : qb;
    ushort_t* pw = &Plds[w][c * 72];
    const unsigned bxor = (unsigned)((c & 7) << 4);

    const int srow = t >> 3, sb = (t & 7) * 16;
#define STAGE_KV(ST)                                                                \
    {                                                                               \
        const int S0_ = (ST) * 64;                                                  \
        _Pragma("unroll") for (int j = 0; j < 2; ++j) {                             \
            int r = j * 32 + srow;                                                  \
            int bs = sb ^ ((r & 7) << 4);                                           \
            gload_lds16(kpB + (size_t)(S0_ + r) * 128 + bs,                         \
                        (char*)Ks + r * 128 + sb);                                  \
            gload_lds16(vpB + (size_t)r * (TSEQ * 2) + S0_ * 2 + bs,                \
                        (char*)Vs + r * 128 + sb);                                  \
        }                                                                           \
    }

    STAGE_KV(st0);
    for (int st = st0; st <= send; ++st) {
        const int S0 = st * 64;
        __syncthreads();

        __builtin_amdgcn_s_setprio(1);
        f32x4 sa[4];
#pragma unroll
        for (int sub = 0; sub < 4; ++sub) {
            const char* kr = (const char*)Ks + (16 * sub + c) * 128;
            short8 k0 = *(const short8*)(kr + ((g * 16) ^ bxor));
            short8 k1 = *(const short8*)(kr + ((64 + g * 16) ^ bxor));
            f32x4 t0 = f32x4{0.f, 0.f, 0.f, 0.f};
            t0 = __builtin_amdgcn_mfma_f32_16x16x32_bf16(k0, bq0, t0, 0, 0, 0);
            t0 = __builtin_amdgcn_mfma_f32_16x16x32_bf16(k1, bq1, t0, 0, 0, 0);
            sa[sub] = t0;
        }
        __builtin_amdgcn_s_setprio(0);

        float pvv[16];
#pragma unroll
        for (int sub = 0; sub < 4; ++sub)
#pragma unroll
            for (int i = 0; i < 4; ++i) pvv[4 * sub + i] = sa[sub][i];
        if (st == qb) {
#pragma unroll
            for (int sub = 0; sub < 4; ++sub)
#pragma unroll
                for (int i = 0; i < 4; ++i)
                    if (S0 + 16 * sub + 4 * g + i > q0 + c) pvv[4 * sub + i] = -INFINITY;
        }
        float tmax = pvv[0];
#pragma unroll
        for (int j = 1; j < 16; ++j) tmax = fmaxf(tmax, pvv[j]);
        tmax = fmaxf(tmax, __shfl_xor(tmax, 16));
        tmax = fmaxf(tmax, __shfl_xor(tmax, 32));
        if (!__all(tmax - m_ <= 8.0f)) {
            float mn = fmaxf(m_, tmax);
            float fac = __expf(m_ - mn);
            m_ = mn;
            l_ *= fac;
#pragma unroll
            for (int i = 0; i < 4; ++i) {
                float fr = __shfl(fac, 4 * g + i);
#pragma unroll
                for (int nf = 0; nf < 4; ++nf) o[nf][i] *= fr;
            }
        }
        float pp[16], rs = 0.f;
#pragma unroll
        for (int j = 0; j < 16; ++j) { pp[j] = __expf(pvv[j] - m_); rs += pp[j]; }
        rs += __shfl_xor(rs, 16);
        rs += __shfl_xor(rs, 32);
        l_ += rs;

#pragma unroll
        for (int sub = 0; sub < 4; ++sub) {
            unsigned lo = (__float_as_uint(pp[4 * sub + 0]) >> 16) |
                          (__float_as_uint(pp[4 * sub + 1]) & 0xffff0000u);
            unsigned hi = (__float_as_uint(pp[4 * sub + 2]) >> 16) |
                          (__float_as_uint(pp[4 * sub + 3]) & 0xffff0000u);
            *(uint2*)(pw + 16 * sub + 4 * g) = make_uint2(lo, hi);
        }
        asm volatile("s_waitcnt lgkmcnt(0)" ::: "memory");
        short8 pa0 = *(const short8*)(&Plds[w][c * 72 + g * 8]);
        short8 pa1 = *(const short8*)(&Plds[w][c * 72 + 32 + g * 8]);

        __builtin_amdgcn_s_setprio(1);
#pragma unroll
        for (int nf = 0; nf < 4; ++nf) {
            const char* vr = (const char*)Vs + (nf * 16 + c) * 128;
            short8 v0 = *(const short8*)(vr + ((g * 16) ^ bxor));
            short8 v1 = *(const short8*)(vr + ((64 + g * 16) ^ bxor));
            o[nf] = __builtin_amdgcn_mfma_f32_16x16x32_bf16(pa0, v0, o[nf], 0, 0, 0);
            o[nf] = __builtin_amdgcn_mfma_f32_16x16x32_bf16(pa1, v1, o[nf], 0, 0, 0);
        }
        __builtin_amdgcn_s_setprio(0);

        __syncthreads();
        if (st < send) STAGE_KV(st + 1);
    }
#undef STAGE_KV

    if (qb < 8) {
#pragma unroll
        for (int i = 0; i < 4; ++i) {
            float rl = 1.0f / __shfl(l_, 4 * g + i);
            int tt = q0 + 4 * g + i;
#pragma unroll
            for (int nf = 0; nf < 4; ++nf)
                attout[((size_t)(bb * TSEQ + tt)) * CC + hh * DH + nf * 16 + c] =
                    f2bf(o[nf][i] * rl);
        }
    } else {
        const size_t slot = (size_t)(bh * 32 + qb) * 4 + sc;
        float* op = opart + slot * 4096;
#pragma unroll
        for (int nf = 0; nf < 4; ++nf)
#pragma unroll
            for (int i = 0; i < 4; ++i)
                op[(size_t)(w * 16 + 4 * g + i) * 64 + nf * 16 + c] = o[nf][i];
        if (g == 0) {
            mlpart[slot * 128 + w * 16 + c] = m_;
            mlpart[slot * 128 + 64 + w * 16 + c] = l_;
        }
    }
}

// ---------------------------------------------------------------------------
// Combine partials for qb >= 8.  grid (B*H, 24) -> qb = blockIdx.y + 8.
// ---------------------------------------------------------------------------
__global__ __launch_bounds__(256) void flash_combine(
    const float* __restrict__ opart, const float* __restrict__ mlpart,
    ushort_t* __restrict__ attout)
{
    const int bh = blockIdx.x, qb = blockIdx.y + 8;
    const int bb = bh >> 4, hh = bh & 15;
    const int nsc = (qb >> 3) + 1;
    const int t = threadIdx.x, r = t >> 2, qc = t & 3;
    const size_t slot0 = (size_t)(bh * 32 + qb) * 4;

    float mi[4], li[4];
    float M = -INFINITY;
#pragma unroll
    for (int i = 0; i < 4; ++i) {
        if (i < nsc) {
            mi[i] = mlpart[(slot0 + i) * 128 + r];
            li[i] = mlpart[(slot0 + i) * 128 + 64 + r];
            M = fmaxf(M, mi[i]);
        }
    }
    float L = 0.f;
    f32x4 acc[4];
#pragma unroll
    for (int j = 0; j < 4; ++j) acc[j] = f32x4{0.f, 0.f, 0.f, 0.f};
#pragma unroll
    for (int i = 0; i < 4; ++i) {
        if (i < nsc) {
            float F = __expf(mi[i] - M);
            L += li[i] * F;
            const f32x4* orow = (const f32x4*)(opart + (slot0 + i) * 4096 +
                                               (size_t)r * 64 + qc * 16);
#pragma unroll
            for (int j = 0; j < 4; ++j) acc[j] += orow[j] * F;
        }
    }
    float rl = 1.0f / L;
    unsigned wb[8];
#pragma unroll
    for (int j = 0; j < 4; ++j) {
        wb[2 * j] = (unsigned)f2bf(acc[j][0] * rl) | ((unsigned)f2bf(acc[j][1] * rl) << 16);
        wb[2 * j + 1] = (unsigned)f2bf(acc[j][2] * rl) | ((unsigned)f2bf(acc[j][3] * rl) << 16);
    }
    ushort_t* dst = attout + ((size_t)(bb * TSEQ + qb * 64 + r)) * CC + hh * DH + qc * 16;
    ((uint4*)dst)[0] = make_uint4(wb[0], wb[1], wb[2], wb[3]);
    ((uint4*)dst)[1] = make_uint4(wb[4], wb[5], wb[6], wb[7]);
}

// ---------------------------------------------------------------------------
extern "C" void kernel_launch(void* const* d_in, const int* in_sizes, int n_in,
                              void* d_out, int out_size, void* d_ws, size_t ws_size,
                              hipStream_t stream)
{
    (void)in_sizes; (void)n_in; (void)out_size; (void)ws_size;
    const float* x     = (const float*)d_in[0];
    const float* ln1_g = (const float*)d_in[1];
    const float* ln1_b = (const float*)d_in[2];
    const float* Wq    = (const float*)d_in[3];
    const float* Wk    = (const float*)d_in[4];
    const float* Wv    = (const float*)d_in[5];
    const float* Wo    = (const float*)d_in[6];
    const float* bo    = (const float*)d_in[7];
    const float* ln2_g = (const float*)d_in[8];
    const float* ln2_b = (const float*)d_in[9];
    const float* W1    = (const float*)d_in[10];
    const float* b1    = (const float*)d_in[11];
    const float* W2    = (const float*)d_in[12];
    const float* b2    = (const float*)d_in[13];

    char* p = (char*)d_ws;
    ushort_t* hbuf  = (ushort_t*)p;  p += (size_t)BT * CC * 2;
    ushort_t* WqkvT = (ushort_t*)p;  p += (size_t)3 * CC * CC * 2;
    ushort_t* WoT   = (ushort_t*)p;  p += (size_t)CC * CC * 2;
    ushort_t* W1T   = (ushort_t*)p;  p += (size_t)CC * HID * 2;
    ushort_t* W2T   = (ushort_t*)p;  p += (size_t)HID * CC * 2;
    ushort_t* Qb    = (ushort_t*)p;  p += (size_t)BT * CC * 2;
    ushort_t* Kbuf  = (ushort_t*)p;  p += (size_t)BT * CC * 2;
    ushort_t* Vt    = (ushort_t*)p;  p += (size_t)BT * CC * 2;
    ushort_t* atto  = (ushort_t*)p;  p += (size_t)BT * CC * 2;
    float*    x1    = (float*)p;     p += (size_t)BT * CC * 4;
    ushort_t* h2    = (ushort_t*)p;  p += (size_t)BT * CC * 2;
    ushort_t* mid   = (ushort_t*)p;  p += (size_t)BT * HID * 2;
    float*    opart = (float*)p;     p += (size_t)4096 * 4096 * 4;   // flash partials / FFN2 bf16 partials
    float*    mlprt = (float*)p;     p += (size_t)4096 * 128 * 4;

    dim3 blk(256);
    transpose_qkv<<<dim3(DH / 32, CC / 32, 3 * NH), blk, 0, stream>>>(Wq, Wk, Wv, WqkvT);
    transpose_cvt<<<dim3(CC / 32, CC / 32, 1), blk, 0, stream>>>(Wo, WoT, CC, CC);
    transpose_cvt<<<dim3(HID / 32, CC / 32, 1), blk, 0, stream>>>(W1, W1T, CC, HID);
    transpose_cvt<<<dim3(CC / 32, HID / 32, 1), blk, 0, stream>>>(W2, W2T, HID, CC);

    ln_kernel<<<dim3(BT), blk, 0, stream>>>(x, ln1_g, ln1_b, hbuf);
    // QKV: [4096]x[3072]x[1024], 128^2 D=2
    gemm_tile<128, 128, 2, 2, 4, 4, 2, 2><<<dim3(BT / 128, 3072 / 128), blk, 0, stream>>>(
        hbuf, WqkvT, 3072, CC, CC, CC, nullptr, nullptr, Qb, Kbuf, Vt);
    flash_split<<<dim3(2 * NH, TSEQ / 64, 4), blk, 0, stream>>>(
        Qb, Kbuf, Vt, opart, mlprt, atto);
    flash_combine<<<dim3(2 * NH, TSEQ / 64 - 8), blk, 0, stream>>>(opart, mlprt, atto);
    // out projection + residual -> x1 (f32), 128x64 D=3
    gemm_tile<128, 64, 4, 1, 2, 4, 0, 3><<<dim3(BT / 128, CC / 64), blk, 0, stream>>>(
        atto, WoT, CC, CC, CC, CC, bo, x, (void*)x1, nullptr, nullptr);
    ln_kernel<<<dim3(BT), blk, 0, stream>>>(x1, ln2_g, ln2_b, h2);
    // FFN1: relu(h2 @ W1 + b1) -> mid, 128^2 D=2
    gemm_tile<128, 128, 2, 2, 4, 4, 1, 2><<<dim3(BT / 128, HID / 128), blk, 0, stream>>>(
        h2, W1T, HID, CC, CC, CC, b1, nullptr, (void*)mid, nullptr, nullptr);
    // FFN2 split-K: 2 chunks of K=2048 -> bf16 partials, 128x64 D=3, grid 32x16x2
    gemm_tile<128, 64, 4, 1, 2, 4, 3, 3><<<dim3(BT / 128, CC / 64, 2), blk, 0, stream>>>(
        mid, W2T, CC, HID / 2, HID, HID, nullptr, nullptr, (void*)opart, nullptr, nullptr);
    ffn2_combine<<<dim3(BT * CC / 8 / 256), blk, 0, stream>>>(
        (const ushort_t*)opart, b2, x1, (float*)d_out);
}

// Round 21
// 253.198 us; speedup vs baseline: 1.1433x; 1.0134x over previous
//
#include <hip/hip_runtime.h>

typedef unsigned short ushort_t;
typedef __attribute__((ext_vector_type(8))) short short8;
typedef __attribute__((ext_vector_type(4))) float f32x4;

#define BT 4096
#define TSEQ 2048
#define CC 1024
#define NH 16
#define DH 64
#define HID 4096
#define ATT_SCALE 0.03125f   /* C^-0.5 = 1/32 (reference scales by C, not DH) */

__device__ __forceinline__ ushort_t f2bf(float f) {
    unsigned u = __float_as_uint(f);
    u = u + 0x7fffu + ((u >> 16) & 1u);
    return (ushort_t)(u >> 16);
}
__device__ __forceinline__ float bf2f(ushort_t u) {
    return __uint_as_float(((unsigned)u) << 16);
}

typedef const __attribute__((address_space(1))) unsigned int* gptr_t;
typedef __attribute__((address_space(3))) unsigned int* lptr_t;
__device__ __forceinline__ void gload_lds16(const void* g, void* l) {
    __builtin_amdgcn_global_load_lds((gptr_t)g, (lptr_t)l, 16, 0, 0);
}

template <int N> __device__ __forceinline__ void vmcnt_wait() {
    if constexpr (N == 0)      asm volatile("s_waitcnt vmcnt(0)" ::: "memory");
    else if constexpr (N == 3) asm volatile("s_waitcnt vmcnt(3)" ::: "memory");
    else if constexpr (N == 4) asm volatile("s_waitcnt vmcnt(4)" ::: "memory");
    else if constexpr (N == 6) asm volatile("s_waitcnt vmcnt(6)" ::: "memory");
    else static_assert(N == 0, "unsupported vmcnt");
}

// ---------------------------------------------------------------------------
// Tiled transpose + f32->bf16 convert:  in [R][Cn] f32  ->  out [Cn][R] bf16
// ---------------------------------------------------------------------------
__global__ __launch_bounds__(256) void transpose_cvt(
    const float* __restrict__ in, ushort_t* __restrict__ out, int R, int Cn)
{
    __shared__ float tile[32][33];
    size_t off = (size_t)blockIdx.z * R * Cn;
    int c0 = blockIdx.x * 32, r0 = blockIdx.y * 32;
    int tx = threadIdx.x & 31, ty = threadIdx.x >> 5;
#pragma unroll
    for (int q = 0; q < 4; ++q)
        tile[ty + 8 * q][tx] = in[off + (size_t)(r0 + ty + 8 * q) * Cn + c0 + tx];
    __syncthreads();
#pragma unroll
    for (int q = 0; q < 4; ++q)
        out[off + (size_t)(c0 + ty + 8 * q) * R + r0 + tx] = f2bf(tile[tx][ty + 8 * q]);
}

// QKV weight transpose, merged: z = mat*16 + head; [C][64] -> [64][C] per head
__global__ __launch_bounds__(256) void transpose_qkv(
    const float* __restrict__ Wq, const float* __restrict__ Wk,
    const float* __restrict__ Wv, ushort_t* __restrict__ WqkvT)
{
    __shared__ float tile[32][33];
    int z = blockIdx.z, mat = z >> 4, head = z & 15;
    const float* in = (mat == 0 ? Wq : (mat == 1 ? Wk : Wv)) + (size_t)head * CC * DH;
    ushort_t* out = WqkvT + (size_t)z * DH * CC;
    int c0 = blockIdx.x * 32, r0 = blockIdx.y * 32;
    int tx = threadIdx.x & 31, ty = threadIdx.x >> 5;
#pragma unroll
    for (int q = 0; q < 4; ++q)
        tile[ty + 8 * q][tx] = in[(size_t)(r0 + ty + 8 * q) * DH + c0 + tx];
    __syncthreads();
#pragma unroll
    for (int q = 0; q < 4; ++q)
        out[(size_t)(c0 + ty + 8 * q) * CC + r0 + tx] = f2bf(tile[tx][ty + 8 * q]);
}

// ---------------------------------------------------------------------------
// LayerNorm row kernel: x f32 [rows][1024] -> out bf16.
// ---------------------------------------------------------------------------
__global__ __launch_bounds__(256) void ln_kernel(
    const float* __restrict__ x, const float* __restrict__ g,
    const float* __restrict__ b, ushort_t* __restrict__ out)
{
    int row = blockIdx.x;
    const float4 xv = ((const float4*)(x + (size_t)row * CC))[threadIdx.x];
    float s = xv.x + xv.y + xv.z + xv.w;
    float s2 = xv.x * xv.x + xv.y * xv.y + xv.z * xv.z + xv.w * xv.w;
#pragma unroll
    for (int d = 1; d < 64; d <<= 1) {
        s += __shfl_xor(s, d);
        s2 += __shfl_xor(s2, d);
    }
    __shared__ float ps[4], ps2[4];
    int w = threadIdx.x >> 6, lane = threadIdx.x & 63;
    if (lane == 0) { ps[w] = s; ps2[w] = s2; }
    __syncthreads();
    s = ps[0] + ps[1] + ps[2] + ps[3];
    s2 = ps2[0] + ps2[1] + ps2[2] + ps2[3];
    float mu = s * (1.0f / CC);
    float var = s2 * (1.0f / CC) - mu * mu;
    float rs = rsqrtf(var + 1e-5f);
    int c = threadIdx.x * 4;
    const float4 gv = ((const float4*)g)[threadIdx.x];
    const float4 bv = ((const float4*)b)[threadIdx.x];
    ushort_t u0 = f2bf((xv.x - mu) * rs * gv.x + bv.x);
    ushort_t u1 = f2bf((xv.y - mu) * rs * gv.y + bv.y);
    ushort_t u2 = f2bf((xv.z - mu) * rs * gv.z + bv.z);
    ushort_t u3 = f2bf((xv.w - mu) * rs * gv.w + bv.w);
    unsigned lo = (unsigned)u0 | ((unsigned)u1 << 16);
    unsigned hi = (unsigned)u2 | ((unsigned)u3 << 16);
    ((uint2*)(out + (size_t)row * CC + c))[0] = make_uint2(lo, hi);
}

// ---------------------------------------------------------------------------
// LDS-staged NT GEMM, depth-D ring buffer with COUNTED vmcnt.
// MODE 0: f32 out = acc + bias[n] + resid[m][n]
// MODE 1: bf16 out = relu(acc + bias[n])
// MODE 2: QKV scatter (Q prescaled by ATT_SCALE)
// MODE 3: split-K bf16 partial at plane blockIdx.z (A/B column offset z*K)
// ---------------------------------------------------------------------------
template <int BM, int BN, int WM, int WN, int MR, int NR, int MODE, int D>
__global__ __launch_bounds__(256) void gemm_tile(
    const ushort_t* __restrict__ A, const ushort_t* __restrict__ Bt,
    int N, int K, int lda, int ldb,
    const float* __restrict__ bias, const float* __restrict__ resid,
    void* __restrict__ out0, void* __restrict__ out1, void* __restrict__ out2)
{
    static_assert(WM * WN == 4 && WM * MR * 16 == BM && WN * NR * 16 == BN, "geom");
    constexpr int L = BM / 64 + BN / 64;
    __shared__ ushort_t As[D][BM * 32];
    __shared__ ushort_t Bs[D][BN * 32];

    const int t = threadIdx.x;
    const int w = t >> 6, lane = t & 63, g = lane >> 4, c = lane & 15;
    const int wr = w / WN, wc = w % WN;
    const int m0 = blockIdx.x * BM;
    const int n0 = blockIdx.y * BN;
    if (MODE == 3) {   // K-chunk column offset
        A += (size_t)blockIdx.z * K;
        Bt += (size_t)blockIdx.z * K;
    }

    f32x4 acc[MR][NR];
#pragma unroll
    for (int mi = 0; mi < MR; ++mi)
#pragma unroll
        for (int ni = 0; ni < NR; ++ni) acc[mi][ni] = f32x4{0.f, 0.f, 0.f, 0.f};

    const int arow = t >> 2, acol = (t & 3) * 8;
    const int aoff = (wr * MR * 16 + c) * 32 + g * 8;
    const int boff = (wc * NR * 16 + c) * 32 + g * 8;

#define STAGE(BUF, K0)                                                          \
    {                                                                           \
        _Pragma("unroll") for (int j = 0; j < BM / 64; ++j)                     \
            gload_lds16(A + (size_t)(m0 + j * 64 + arow) * lda + (K0) + acol,   \
                        As[BUF] + (size_t)j * 2048 + t * 8);                    \
        _Pragma("unroll") for (int j = 0; j < BN / 64; ++j)                     \
            gload_lds16(Bt + (size_t)(n0 + j * 64 + arow) * ldb + (K0) + acol,  \
                        Bs[BUF] + (size_t)j * 2048 + t * 8);                    \
    }

    const int nt = K >> 5;
#pragma unroll
    for (int d = 0; d < D - 1; ++d) STAGE(d, d * 32);

    int cur = 0;
    for (int ti = 0; ti < nt; ++ti) {
        const int ahead = nt - 1 - ti;
        if (ahead >= D - 1) {
            const int stg = (cur == 0) ? D - 1 : cur - 1;
            STAGE(stg, (ti + D - 1) * 32);
            vmcnt_wait<(D - 1) * L>();
        } else if (D == 3 && ahead == 1) {
            vmcnt_wait<L>();
        } else {
            vmcnt_wait<0>();
        }
        __builtin_amdgcn_sched_barrier(0);
        __builtin_amdgcn_s_barrier();

        const ushort_t* Ard = As[cur] + aoff;
        const ushort_t* Brd = Bs[cur] + boff;
        short8 af[MR], bf[NR];
#pragma unroll
        for (int mi = 0; mi < MR; ++mi) af[mi] = *(const short8*)(Ard + mi * 512);
#pragma unroll
        for (int ni = 0; ni < NR; ++ni) bf[ni] = *(const short8*)(Brd + ni * 512);
        __builtin_amdgcn_s_setprio(1);
#pragma unroll
        for (int mi = 0; mi < MR; ++mi)
#pragma unroll
            for (int ni = 0; ni < NR; ++ni)
                acc[mi][ni] = __builtin_amdgcn_mfma_f32_16x16x32_bf16(
                    af[mi], bf[ni], acc[mi][ni], 0, 0, 0);
        __builtin_amdgcn_s_setprio(0);

        __builtin_amdgcn_sched_barrier(0);
        __builtin_amdgcn_s_barrier();
        cur = (cur + 1 == D) ? 0 : cur + 1;
    }
#undef STAGE

#pragma unroll
    for (int mi = 0; mi < MR; ++mi)
#pragma unroll
        for (int ni = 0; ni < NR; ++ni)
#pragma unroll
            for (int i = 0; i < 4; ++i) {
                int row = m0 + wr * MR * 16 + mi * 16 + g * 4 + i;
                int col = n0 + wc * NR * 16 + ni * 16 + c;
                float v = acc[mi][ni][i];
                if (MODE == 0) {
                    v += bias[col] + resid[(size_t)row * N + col];
                    ((float*)out0)[(size_t)row * N + col] = v;
                } else if (MODE == 1) {
                    v += bias[col];
                    v = v > 0.f ? v : 0.f;
                    ((ushort_t*)out0)[(size_t)row * N + col] = f2bf(v);
                } else if (MODE == 3) {
                    ((ushort_t*)out0)[(size_t)blockIdx.z * BT * N + (size_t)row * N + col] =
                        f2bf(v);
                } else {
                    int bb = row >> 11, tt = row & (TSEQ - 1);
                    if (col < 1024) {
                        int head = col >> 6, d = col & 63;
                        ((ushort_t*)out0)[((size_t)(bb * NH + head) * TSEQ + tt) * DH + d] =
                            f2bf(v * ATT_SCALE);
                    } else if (col < 2048) {
                        int head = (col - 1024) >> 6, d = col & 63;
                        ((ushort_t*)out1)[((size_t)(bb * NH + head) * TSEQ + tt) * DH + d] = f2bf(v);
                    } else {
                        int head = (col - 2048) >> 6, d = col & 63;
                        ((ushort_t*)out2)[((size_t)(bb * NH + head) * DH + d) * TSEQ + tt] = f2bf(v);
                    }
                }
            }
}

// ---------------------------------------------------------------------------
// FFN2 combine: out[m][n] = sum_{z<2} bf16 parts[z][m][n] + bias[n] + resid
// ---------------------------------------------------------------------------
__global__ __launch_bounds__(256) void ffn2_combine(
    const ushort_t* __restrict__ parts, const float* __restrict__ bias,
    const float* __restrict__ resid, float* __restrict__ out)
{
    const size_t off = ((size_t)blockIdx.x * 256 + threadIdx.x) * 8;
    const int col = (int)(off & 1023);
    short8 p0 = *(const short8*)(parts + off);
    short8 p1 = *(const short8*)(parts + (size_t)BT * CC + off);
    float4 r0 = ((const float4*)(resid + off))[0];
    float4 r1 = ((const float4*)(resid + off + 4))[0];
    float4 b0 = ((const float4*)(bias + col))[0];
    float4 b1 = ((const float4*)(bias + col + 4))[0];
    float o[8];
#pragma unroll
    for (int j = 0; j < 8; ++j)
        o[j] = bf2f((ushort_t)p0[j]) + bf2f((ushort_t)p1[j]);
    float4 w0 = make_float4(o[0] + b0.x + r0.x, o[1] + b0.y + r0.y,
                            o[2] + b0.z + r0.z, o[3] + b0.w + r0.w);
    float4 w1 = make_float4(o[4] + b1.x + r1.x, o[5] + b1.y + r1.y,
                            o[6] + b1.z + r1.z, o[7] + b1.w + r1.w);
    ((float4*)(out + off))[0] = w0;
    ((float4*)(out + off + 4))[0] = w1;
}

// ---------------------------------------------------------------------------
// Split flash: K/V tiles staged per block into LDS (global_load_lds,
// inverse-swizzled source), shared by 4 waves.  grid (B*H, T/64, 4 chunks).
// ---------------------------------------------------------------------------
__global__ __launch_bounds__(256) void flash_split(
    const ushort_t* __restrict__ Q, const ushort_t* __restrict__ Kb,
    const ushort_t* __restrict__ Vt, float* __restrict__ opart,
    float* __restrict__ mlpart, ushort_t* __restrict__ attout)
{
    __shared__ ushort_t Ks[64 * 64];
    __shared__ ushort_t Vs[64 * 64];
    __shared__ ushort_t Plds[4][16 * 72];
    const int t = threadIdx.x;
    const int w = t >> 6, lane = t & 63;
    const int g = lane >> 4, c = lane & 15;
    const int bh = blockIdx.x, qb = blockIdx.y, sc = blockIdx.z;
    if (sc * 8 > qb) return;
    const int bb = bh >> 4, hh = bh & 15;
    const int q0 = qb * 64 + w * 16;
    const ushort_t* qp = Q + (size_t)bh * TSEQ * DH;
    const char* kpB = (const char*)(Kb + (size_t)bh * TSEQ * DH);
    const char* vpB = (const char*)(Vt + (size_t)bh * DH * TSEQ);

    const short8 bq0 = *(const short8*)(qp + (size_t)(q0 + c) * DH + g * 8);
    const short8 bq1 = *(const short8*)(qp + (size_t)(q0 + c) * DH + 32 + g * 8);

    float m_ = -INFINITY, l_ = 0.f;
    f32x4 o[4];
#pragma unroll
    for (int nf = 0; nf < 4; ++nf) o[nf] = f32x4{0.f, 0.f, 0.f, 0.f};

    const int st0 = sc * 8;
    const int send = (st0 + 7 < qb) ? st0 + 7 : qb;
    ushort_t* pw = &Plds[w][c * 72];
    const unsigned bxor = (unsigned)((c & 7) << 4);

    const int srow = t >> 3, sb = (t & 7) * 16;
#define STAGE_KV(ST)                                                                \
    {                                                                               \
        const int S0_ = (ST) * 64;                                                  \
        _Pragma("unroll") for (int j = 0; j < 2; ++j) {                             \
            int r = j * 32 + srow;                                                  \
            int bs = sb ^ ((r & 7) << 4);                                           \
            gload_lds16(kpB + (size_t)(S0_ + r) * 128 + bs,                         \
                        (char*)Ks + r * 128 + sb);                                  \
            gload_lds16(vpB + (size_t)r * (TSEQ * 2) + S0_ * 2 + bs,                \
                        (char*)Vs + r * 128 + sb);                                  \
        }                                                                           \
    }

    STAGE_KV(st0);
    for (int st = st0; st <= send; ++st) {
        const int S0 = st * 64;
        __syncthreads();

        __builtin_amdgcn_s_setprio(1);
        f32x4 sa[4];
#pragma unroll
        for (int sub = 0; sub < 4; ++sub) {
            const char* kr = (const char*)Ks + (16 * sub + c) * 128;
            short8 k0 = *(const short8*)(kr + ((g * 16) ^ bxor));
            short8 k1 = *(const short8*)(kr + ((64 + g * 16) ^ bxor));
            f32x4 t0 = f32x4{0.f, 0.f, 0.f, 0.f};
            t0 = __builtin_amdgcn_mfma_f32_16x16x32_bf16(k0, bq0, t0, 0, 0, 0);
            t0 = __builtin_amdgcn_mfma_f32_16x16x32_bf16(k1, bq1, t0, 0, 0, 0);
            sa[sub] = t0;
        }
        __builtin_amdgcn_s_setprio(0);

        float pvv[16];
#pragma unroll
        for (int sub = 0; sub < 4; ++sub)
#pragma unroll
            for (int i = 0; i < 4; ++i) pvv[4 * sub + i] = sa[sub][i];
        if (st == qb) {
#pragma unroll
            for (int sub = 0; sub < 4; ++sub)
#pragma unroll
                for (int i = 0; i < 4; ++i)
                    if (S0 + 16 * sub + 4 * g + i > q0 + c) pvv[4 * sub + i] = -INFINITY;
        }
        float tmax = pvv[0];
#pragma unroll
        for (int j = 1; j < 16; ++j) tmax = fmaxf(tmax, pvv[j]);
        tmax = fmaxf(tmax, __shfl_xor(tmax, 16));
        tmax = fmaxf(tmax, __shfl_xor(tmax, 32));
        if (!__all(tmax - m_ <= 8.0f)) {
            float mn = fmaxf(m_, tmax);
            float fac = __expf(m_ - mn);
            m_ = mn;
            l_ *= fac;
#pragma unroll
            for (int i = 0; i < 4; ++i) {
                float fr = __shfl(fac, 4 * g + i);
#pragma unroll
                for (int nf = 0; nf < 4; ++nf) o[nf][i] *= fr;
            }
        }
        float pp[16], rs = 0.f;
#pragma unroll
        for (int j = 0; j < 16; ++j) { pp[j] = __expf(pvv[j] - m_); rs += pp[j]; }
        rs += __shfl_xor(rs, 16);
        rs += __shfl_xor(rs, 32);
        l_ += rs;

#pragma unroll
        for (int sub = 0; sub < 4; ++sub) {
            unsigned lo = (__float_as_uint(pp[4 * sub + 0]) >> 16) |
                          (__float_as_uint(pp[4 * sub + 1]) & 0xffff0000u);
            unsigned hi = (__float_as_uint(pp[4 * sub + 2]) >> 16) |
                          (__float_as_uint(pp[4 * sub + 3]) & 0xffff0000u);
            *(uint2*)(pw + 16 * sub + 4 * g) = make_uint2(lo, hi);
        }
        asm volatile("s_waitcnt lgkmcnt(0)" ::: "memory");
        short8 pa0 = *(const short8*)(&Plds[w][c * 72 + g * 8]);
        short8 pa1 = *(const short8*)(&Plds[w][c * 72 + 32 + g * 8]);

        __builtin_amdgcn_s_setprio(1);
#pragma unroll
        for (int nf = 0; nf < 4; ++nf) {
            const char* vr = (const char*)Vs + (nf * 16 + c) * 128;
            short8 v0 = *(const short8*)(vr + ((g * 16) ^ bxor));
            short8 v1 = *(const short8*)(vr + ((64 + g * 16) ^ bxor));
            o[nf] = __builtin_amdgcn_mfma_f32_16x16x32_bf16(pa0, v0, o[nf], 0, 0, 0);
            o[nf] = __builtin_amdgcn_mfma_f32_16x16x32_bf16(pa1, v1, o[nf], 0, 0, 0);
        }
        __builtin_amdgcn_s_setprio(0);

        __syncthreads();
        if (st < send) STAGE_KV(st + 1);
    }
#undef STAGE_KV

    if (qb < 8) {
#pragma unroll
        for (int i = 0; i < 4; ++i) {
            float rl = 1.0f / __shfl(l_, 4 * g + i);
            int tt = q0 + 4 * g + i;
#pragma unroll
            for (int nf = 0; nf < 4; ++nf)
                attout[((size_t)(bb * TSEQ + tt)) * CC + hh * DH + nf * 16 + c] =
                    f2bf(o[nf][i] * rl);
        }
    } else {
        const size_t slot = (size_t)(bh * 32 + qb) * 4 + sc;
        float* op = opart + slot * 4096;
#pragma unroll
        for (int nf = 0; nf < 4; ++nf)
#pragma unroll
            for (int i = 0; i < 4; ++i)
                op[(size_t)(w * 16 + 4 * g + i) * 64 + nf * 16 + c] = o[nf][i];
        if (g == 0) {
            mlpart[slot * 128 + w * 16 + c] = m_;
            mlpart[slot * 128 + 64 + w * 16 + c] = l_;
        }
    }
}

// ---------------------------------------------------------------------------
// Combine partials for qb >= 8.  grid (B*H, 24) -> qb = blockIdx.y + 8.
// ---------------------------------------------------------------------------
__global__ __launch_bounds__(256) void flash_combine(
    const float* __restrict__ opart, const float* __restrict__ mlpart,
    ushort_t* __restrict__ attout)
{
    const int bh = blockIdx.x, qb = blockIdx.y + 8;
    const int bb = bh >> 4, hh = bh & 15;
    const int nsc = (qb >> 3) + 1;
    const int t = threadIdx.x, r = t >> 2, qc = t & 3;
    const size_t slot0 = (size_t)(bh * 32 + qb) * 4;

    float mi[4], li[4];
    float M = -INFINITY;
#pragma unroll
    for (int i = 0; i < 4; ++i) {
        if (i < nsc) {
            mi[i] = mlpart[(slot0 + i) * 128 + r];
            li[i] = mlpart[(slot0 + i) * 128 + 64 + r];
            M = fmaxf(M, mi[i]);
        }
    }
    float L = 0.f;
    f32x4 acc[4];
#pragma unroll
    for (int j = 0; j < 4; ++j) acc[j] = f32x4{0.f, 0.f, 0.f, 0.f};
#pragma unroll
    for (int i = 0; i < 4; ++i) {
        if (i < nsc) {
            float F = __expf(mi[i] - M);
            L += li[i] * F;
            const f32x4* orow = (const f32x4*)(opart + (slot0 + i) * 4096 +
                                               (size_t)r * 64 + qc * 16);
#pragma unroll
            for (int j = 0; j < 4; ++j) acc[j] += orow[j] * F;
        }
    }
    float rl = 1.0f / L;
    unsigned wb[8];
#pragma unroll
    for (int j = 0; j < 4; ++j) {
        wb[2 * j] = (unsigned)f2bf(acc[j][0] * rl) | ((unsigned)f2bf(acc[j][1] * rl) << 16);
        wb[2 * j + 1] = (unsigned)f2bf(acc[j][2] * rl) | ((unsigned)f2bf(acc[j][3] * rl) << 16);
    }
    ushort_t* dst = attout + ((size_t)(bb * TSEQ + qb * 64 + r)) * CC + hh * DH + qc * 16;
    ((uint4*)dst)[0] = make_uint4(wb[0], wb[1], wb[2], wb[3]);
    ((uint4*)dst)[1] = make_uint4(wb[4], wb[5], wb[6], wb[7]);
}

// ---------------------------------------------------------------------------
extern "C" void kernel_launch(void* const* d_in, const int* in_sizes, int n_in,
                              void* d_out, int out_size, void* d_ws, size_t ws_size,
                              hipStream_t stream)
{
    (void)in_sizes; (void)n_in; (void)out_size; (void)ws_size;
    const float* x     = (const float*)d_in[0];
    const float* ln1_g = (const float*)d_in[1];
    const float* ln1_b = (const float*)d_in[2];
    const float* Wq    = (const float*)d_in[3];
    const float* Wk    = (const float*)d_in[4];
    const float* Wv    = (const float*)d_in[5];
    const float* Wo    = (const float*)d_in[6];
    const float* bo    = (const float*)d_in[7];
    const float* ln2_g = (const float*)d_in[8];
    const float* ln2_b = (const float*)d_in[9];
    const float* W1    = (const float*)d_in[10];
    const float* b1    = (const float*)d_in[11];
    const float* W2    = (const float*)d_in[12];
    const float* b2    = (const float*)d_in[13];

    char* p = (char*)d_ws;
    ushort_t* hbuf  = (ushort_t*)p;  p += (size_t)BT * CC * 2;
    ushort_t* WqkvT = (ushort_t*)p;  p += (size_t)3 * CC * CC * 2;
    ushort_t* WoT   = (ushort_t*)p;  p += (size_t)CC * CC * 2;
    ushort_t* W1T   = (ushort_t*)p;  p += (size_t)CC * HID * 2;
    ushort_t* W2T   = (ushort_t*)p;  p += (size_t)HID * CC * 2;
    ushort_t* Qb    = (ushort_t*)p;  p += (size_t)BT * CC * 2;
    ushort_t* Kbuf  = (ushort_t*)p;  p += (size_t)BT * CC * 2;
    ushort_t* Vt    = (ushort_t*)p;  p += (size_t)BT * CC * 2;
    ushort_t* atto  = (ushort_t*)p;  p += (size_t)BT * CC * 2;
    float*    x1    = (float*)p;     p += (size_t)BT * CC * 4;
    ushort_t* h2    = (ushort_t*)p;  p += (size_t)BT * CC * 2;
    ushort_t* mid   = (ushort_t*)p;  p += (size_t)BT * HID * 2;
    float*    opart = (float*)p;     p += (size_t)4096 * 4096 * 4;   // flash partials / FFN2 bf16 partials
    float*    mlprt = (float*)p;     p += (size_t)4096 * 128 * 4;

    dim3 blk(256);
    transpose_qkv<<<dim3(DH / 32, CC / 32, 3 * NH), blk, 0, stream>>>(Wq, Wk, Wv, WqkvT);
    transpose_cvt<<<dim3(CC / 32, CC / 32, 1), blk, 0, stream>>>(Wo, WoT, CC, CC);
    transpose_cvt<<<dim3(HID / 32, CC / 32, 1), blk, 0, stream>>>(W1, W1T, CC, HID);
    transpose_cvt<<<dim3(CC / 32, HID / 32, 1), blk, 0, stream>>>(W2, W2T, HID, CC);

    ln_kernel<<<dim3(BT), blk, 0, stream>>>(x, ln1_g, ln1_b, hbuf);
    // QKV: [4096]x[3072]x[1024], 128^2 D=2
    gemm_tile<128, 128, 2, 2, 4, 4, 2, 2><<<dim3(BT / 128, 3072 / 128), blk, 0, stream>>>(
        hbuf, WqkvT, 3072, CC, CC, CC, nullptr, nullptr, Qb, Kbuf, Vt);
    flash_split<<<dim3(2 * NH, TSEQ / 64, 4), blk, 0, stream>>>(
        Qb, Kbuf, Vt, opart, mlprt, atto);
    flash_combine<<<dim3(2 * NH, TSEQ / 64 - 8), blk, 0, stream>>>(opart, mlprt, atto);
    // out projection + residual -> x1 (f32), 128x64 D=3
    gemm_tile<128, 64, 4, 1, 2, 4, 0, 3><<<dim3(BT / 128, CC / 64), blk, 0, stream>>>(
        atto, WoT, CC, CC, CC, CC, bo, x, (void*)x1, nullptr, nullptr);
    ln_kernel<<<dim3(BT), blk, 0, stream>>>(x1, ln2_g, ln2_b, h2);
    // FFN1: relu(h2 @ W1 + b1) -> mid, 128^2 D=2
    gemm_tile<128, 128, 2, 2, 4, 4, 1, 2><<<dim3(BT / 128, HID / 128), blk, 0, stream>>>(
        h2, W1T, HID, CC, CC, CC, b1, nullptr, (void*)mid, nullptr, nullptr);
    // FFN2 split-K: 2 chunks of K=2048 -> bf16 partials, 128x64 D=3, grid 32x16x2
    gemm_tile<128, 64, 4, 1, 2, 4, 3, 3><<<dim3(BT / 128, CC / 64, 2), blk, 0, stream>>>(
        mid, W2T, CC, HID / 2, HID, HID, nullptr, nullptr, (void*)opart, nullptr, nullptr);
    ffn2_combine<<<dim3(BT * CC / 8 / 256), blk, 0, stream>>>(
        (const ushort_t*)opart, b2, x1, (float*)d_out);
}